// Round 11
// baseline (627.317 us; speedup 1.0000x reference)
//
#include <hip/hip_runtime.h>
#include <math.h>

// ---------------- problem constants ----------------
constexpr int Bc = 2, Cc = 64, Nc = 50000, Kc = 8;
constexpr int PT = 16;                       // points per wave (MFMA M dim)
constexpr int NBLK = (Bc * Nc) / PT;         // 6250 tiles
constexpr int NPTS = Bc * Nc;                // 100000

// ---------------- ws byte layout ----------------
constexpr int BIAS_PH = 16;                  // f32[64]
constexpr int BIAS_N1 = 272;                 // f32[64]
constexpr int BIAS_DL = 528;                 // f32[32] (sv folded, padded)
constexpr int B_PH  = 1024;                  // 12 frags * 1KB
constexpr int B_N1  = 13312;                 // 12 frags
constexpr int B_DH  = 25600;                 // 6 frags (delta hi)
constexpr int B_DLO = 31744;                 // 6 frags (delta lo)
constexpr int B_N2  = 37888;                 // 72 frags -> ends 111616
constexpr size_t XT_BYTE  = 262144;          // bf16 volume starts here
constexpr size_t XT_USHORTS = (size_t)Bc * 64 * 64 * 64 * 64;   // 64 MB
constexpr size_t HIST_OFF = XT_BYTE + XT_USHORTS * 2;           // 67,371,008
constexpr int    NBINS    = Bc * 4096;                          // 8192
constexpr size_t PERM_OFF = HIST_OFF + (size_t)NBINS * 4;       // 67,403,776
constexpr size_t WS_NEED  = PERM_OFF + (size_t)NPTS * 4;        // ~67.8 MB

using bf16x8 = __attribute__((ext_vector_type(8))) short;
using f32x4  = __attribute__((ext_vector_type(4))) float;

// ---------------- helpers ----------------
__device__ __forceinline__ float gelu_exact(float v) {
    return 0.5f * v * (1.0f + erff(v * 0.70710678118654752f));
}
__device__ __forceinline__ ushort f2bf(float f) {           // RNE f32 -> bf16 bits
    unsigned u = __float_as_uint(f);
    unsigned r = (u + 0x7FFFu + ((u >> 16) & 1u)) >> 16;
    return (ushort)r;
}
__device__ __forceinline__ float bf2f(ushort u) {
    return __uint_as_float(((unsigned)u) << 16);
}

// ---- transposed channel-minor bf16 sampling: 1 cache line per corner ----
__device__ __forceinline__ float sample_tr(const ushort* __restrict__ xtb, int lane,
                                           float gx, float gy, float gz) {
    float ix = fminf(fmaxf((gx + 1.0f) * 31.5f, 0.0f), 63.0f);
    float iy = fminf(fmaxf((gy + 1.0f) * 31.5f, 0.0f), 63.0f);
    float iz = fminf(fmaxf((gz + 1.0f) * 31.5f, 0.0f), 63.0f);
    float fx0 = floorf(ix), fy0 = floorf(iy), fz0 = floorf(iz);
    int x0 = (int)fx0, y0 = (int)fy0, z0 = (int)fz0;
    float fx = ix - fx0, fy = iy - fy0, fz = iz - fz0;
    int dx = (x0 < 63) ? 64 : 0;
    int dy = (y0 < 63) ? 4096 : 0;
    int dz = (z0 < 63) ? 262144 : 0;
    const ushort* r = xtb + ((((z0 << 12) + (y0 << 6) + x0) << 6) + lane);
    float v000 = bf2f(r[0]),       v001 = bf2f(r[dx]);
    float v010 = bf2f(r[dy]),      v011 = bf2f(r[dy + dx]);
    float v100 = bf2f(r[dz]),      v101 = bf2f(r[dz + dx]);
    float v110 = bf2f(r[dz + dy]), v111 = bf2f(r[dz + dy + dx]);
    float c00 = fmaf(fx, v001 - v000, v000);
    float c01 = fmaf(fx, v011 - v010, v010);
    float c10 = fmaf(fx, v101 - v100, v100);
    float c11 = fmaf(fx, v111 - v110, v110);
    float c0  = fmaf(fy, c01 - c00, c00);
    float c1  = fmaf(fy, c11 - c10, c10);
    return fmaf(fz, c1 - c0, c0);
}

// ---- fallback (channel-major f32) sampling ----
__device__ __forceinline__ float sample_cm(const float* __restrict__ xb,
                                           float gx, float gy, float gz) {
    float ix = fminf(fmaxf((gx + 1.0f) * 31.5f, 0.0f), 63.0f);
    float iy = fminf(fmaxf((gy + 1.0f) * 31.5f, 0.0f), 63.0f);
    float iz = fminf(fmaxf((gz + 1.0f) * 31.5f, 0.0f), 63.0f);
    float fx0 = floorf(ix), fy0 = floorf(iy), fz0 = floorf(iz);
    int x0 = (int)fx0, y0 = (int)fy0, z0 = (int)fz0;
    float fx = ix - fx0, fy = iy - fy0, fz = iz - fz0;
    int x1 = (x0 < 63) ? x0 + 1 : 63;
    int dy = (y0 < 63) ? 64 : 0;
    int dz = (z0 < 63) ? 4096 : 0;
    const float* r = xb + ((z0 << 12) + (y0 << 6));
    float v000 = r[x0],           v001 = r[x1];
    float v010 = r[x0 + dy],      v011 = r[x1 + dy];
    float v100 = r[x0 + dz],      v101 = r[x1 + dz];
    float v110 = r[x0 + dy + dz], v111 = r[x1 + dy + dz];
    float c00 = fmaf(fx, v001 - v000, v000);
    float c01 = fmaf(fx, v011 - v010, v010);
    float c10 = fmaf(fx, v101 - v100, v100);
    float c11 = fmaf(fx, v111 - v110, v110);
    float c0  = fmaf(fy, c01 - c00, c00);
    float c1  = fmaf(fy, c11 - c10, c10);
    return fmaf(fz, c1 - c0, c0);
}

// ---------------- spatial sort: bin = batch*4096 + (qz,qy,qx in 16^3) ----------------
__device__ __forceinline__ int point_bin(const float* __restrict__ verts, int i) {
    float gx = verts[i*3], gy = verts[i*3+1], gz = verts[i*3+2];
    int qx = ((int)fminf(fmaxf((gx + 1.0f) * 31.5f, 0.0f), 63.0f)) >> 2;
    int qy = ((int)fminf(fmaxf((gy + 1.0f) * 31.5f, 0.0f), 63.0f)) >> 2;
    int qz = ((int)fminf(fmaxf((gz + 1.0f) * 31.5f, 0.0f), 63.0f)) >> 2;
    int b  = i / Nc;
    return (b << 12) | (qz << 8) | (qy << 4) | qx;
}

__global__ void sb_zero(int* __restrict__ hist) {
    int i = blockIdx.x * blockDim.x + threadIdx.x;
    if (i < NBINS) hist[i] = 0;
}
__global__ void sb_hist(const float* __restrict__ verts, int* __restrict__ hist) {
    int i = blockIdx.x * blockDim.x + threadIdx.x;
    if (i < NPTS) atomicAdd(&hist[point_bin(verts, i)], 1);
}
__global__ __launch_bounds__(1024) void sb_scan(int* __restrict__ hist) {
    __shared__ int part[1024];
    int t = threadIdx.x;
    int v[8];
    int run = 0;
#pragma unroll
    for (int j = 0; j < 8; ++j) {
        int tmp = hist[t * 8 + j];
        v[j] = run; run += tmp;
    }
    part[t] = run;
    __syncthreads();
    if (t == 0) {
        int r2 = 0;
        for (int j = 0; j < 1024; ++j) { int tmp = part[j]; part[j] = r2; r2 += tmp; }
    }
    __syncthreads();
    int base = part[t];
#pragma unroll
    for (int j = 0; j < 8; ++j) hist[t * 8 + j] = base + v[j];
}
__global__ void sb_scatter(const float* __restrict__ verts, int* __restrict__ hist,
                           int* __restrict__ perm) {
    int i = blockIdx.x * blockDim.x + threadIdx.x;
    if (i < NPTS) {
        int pos = atomicAdd(&hist[point_bin(verts, i)], 1);
        perm[pos] = i;
    }
}

// ---------------- weight packing: B-fragment lane order, bf16 (unchanged) ----------------
__global__ void sb_pack(const float* __restrict__ shape_w, const float* __restrict__ shape_b,
                        const float* __restrict__ delta_w, const float* __restrict__ delta_b,
                        const float* __restrict__ ph_w, const float* __restrict__ ph_b,
                        const float* __restrict__ nh1_w, const float* __restrict__ nh1_b,
                        const float* __restrict__ nh2_w, char* __restrict__ wsb) {
    int tid = blockIdx.x * blockDim.x + threadIdx.x;
    int nt  = gridDim.x * blockDim.x;
    float*  bph = (float*)(wsb + BIAS_PH);
    float*  bn1 = (float*)(wsb + BIAS_N1);
    float*  bdl = (float*)(wsb + BIAS_DL);
    ushort* wph = (ushort*)(wsb + B_PH);
    ushort* wn1 = (ushort*)(wsb + B_N1);
    ushort* wdh = (ushort*)(wsb + B_DH);
    ushort* wdl = (ushort*)(wsb + B_DLO);
    ushort* wn2 = (ushort*)(wsb + B_N2);

    for (int e = tid; e < 64; e += nt) { bph[e] = ph_b[e]; bn1[e] = nh1_b[e]; }
    for (int e = tid; e < 32; e += nt) {
        float v = 0.0f;
        if (e < 24) {
            v = delta_b[e];
#pragma unroll
            for (int i = 0; i < 4; ++i) {   // fold shape_vec (constant) into bias, f32 exact
                float sv = 64.0f * (shape_w[i*4] + shape_w[i*4+1] + shape_w[i*4+2] + shape_w[i*4+3])
                         + shape_b[i];
                v += sv * delta_w[e * 71 + 67 + i];
            }
        }
        bdl[e] = v;
    }
    for (int e = tid; e < 6144; e += nt) {
        int frag = e >> 9, lane = (e >> 3) & 63, j = e & 7;
        int kt = frag >> 2, n = frag & 3;
        int k = kt * 32 + ((lane >> 4) << 3) + j;
        int col = n * 16 + (lane & 15);
        wph[e] = (k < 67) ? f2bf(ph_w[col * 67 + k])  : (ushort)0;
        wn1[e] = (k < 67) ? f2bf(nh1_w[col * 67 + k]) : (ushort)0;
    }
    for (int e = tid; e < 3072; e += nt) {
        int frag = e >> 9, lane = (e >> 3) & 63, j = e & 7;
        int kt = frag >> 1, n = frag & 1;
        int k = kt * 32 + ((lane >> 4) << 3) + j;
        int col = n * 16 + (lane & 15);
        float w = (col < 24 && k < 67) ? delta_w[col * 71 + k] : 0.0f;
        ushort hi = f2bf(w);
        wdh[e] = hi;
        wdl[e] = f2bf(w - bf2f(hi));
    }
    for (int e = tid; e < 36864; e += nt) {
        int frag = e >> 9, lane = (e >> 3) & 63, j = e & 7;
        int c9 = frag >> 3, kt = (frag >> 2) & 1, n = frag & 3;
        int k = kt * 32 + ((lane >> 4) << 3) + j;
        int c = n * 16 + (lane & 15);
        wn2[e] = f2bf(nh2_w[(c * 64 + k) * 9 + c9]);
    }
}

// ---------------- transpose x [B,C,64^3] f32 -> xt [B,64^3,C] bf16 (unchanged) ----------------
__global__ __launch_bounds__(256) void sb_transpose(const float* __restrict__ x,
                                                    ushort* __restrict__ xt) {
    __shared__ float tile[64][65];
    int blk = blockIdx.x;
    int b = blk >> 12, zy = blk & 4095;
    const float* __restrict__ src = x + ((size_t)b << 24) + zy * 64;
    unsigned* __restrict__ dst32 = (unsigned*)(xt + ((size_t)b << 24) + (size_t)zy * 4096);
    int t = threadIdx.x;
    int xx = t & 63, c0 = t >> 6;
#pragma unroll
    for (int i = 0; i < 16; ++i) {
        int c = i * 4 + c0;
        tile[c][xx] = src[((size_t)c << 18) + xx];
    }
    __syncthreads();
    int cp = t & 31, xs0 = t >> 5;
#pragma unroll
    for (int i = 0; i < 8; ++i) {
        int xs = i * 8 + xs0;
        unsigned lo = f2bf(tile[cp * 2][xs]);
        unsigned hi = f2bf(tile[cp * 2 + 1][xs]);
        dst32[xs * 32 + cp] = lo | (hi << 16);
    }
}

// ---------------- main MFMA kernel: 1 wave = 16 sorted points ----------------
__global__ __launch_bounds__(64) void sb_main_mfma(
        const ushort* __restrict__ xt, const float* __restrict__ verts,
        const int* __restrict__ perm, const char* __restrict__ wsb,
        float* __restrict__ out) {
    __shared__ __align__(16) ushort stage[PT * 104];  // A tile [point][K..95], pad stride 104
    __shared__ __align__(16) ushort hst[PT * 72];     // gelu(h) A tile
    __shared__ float cst[PT * 4];                     // vertex coords
    __shared__ float dls[PT * 32];                    // delta outputs
    __shared__ int   pidx[PT];                        // original point ids

    const int lane = threadIdx.x;
    const int l15 = lane & 15, lg = lane >> 4;

    // bijective chunked XCD swizzle (m204): consecutive sorted tiles share an XCD L2
    constexpr int NX = 8, Q = NBLK / NX, R = NBLK % NX;   // 781, 2
    const int wg = blockIdx.x;
    const int xcd = wg % NX, idx = wg / NX;
    const int tile = (xcd < R) ? xcd * (Q + 1) + idx : R * (Q + 1) + (xcd - R) * Q + idx;

    const int g0 = tile * PT;                 // position in sorted order
    const int b  = g0 / Nc;                   // batch uniform per tile (50000 % 16 == 0)
    const ushort* __restrict__ xtb = xt + ((size_t)b << 24);

    const float*  bph = (const float*)(wsb + BIAS_PH);
    const float*  bn1 = (const float*)(wsb + BIAS_N1);
    const float*  bdl = (const float*)(wsb + BIAS_DL);
    const ushort* Wph = (const ushort*)(wsb + B_PH);
    const ushort* Wn1 = (const ushort*)(wsb + B_N1);
    const ushort* Wdh = (const ushort*)(wsb + B_DH);
    const ushort* Wdl = (const ushort*)(wsb + B_DLO);
    const ushort* Wn2 = (const ushort*)(wsb + B_N2);

    // zero-init A tile (pad cols 72..103 are MFMA-read vs zero weights; NaN*0=NaN otherwise)
#pragma unroll
    for (int i = 0; i < (PT * 104) / 64; ++i) stage[i * 64 + lane] = 0;

    float bias_p[4], bias_h[4], bias_d[2];
#pragma unroll
    for (int n = 0; n < 4; ++n) { bias_p[n] = bph[n*16 + l15]; bias_h[n] = bn1[n*16 + l15]; }
#pragma unroll
    for (int n = 0; n < 2; ++n) bias_d[n] = bdl[n*16 + l15];

    // init: sorted point ids -> coords -> cst + stage coord block (cols 64..71)
    if (lane < PT) {
        int pid = perm[g0 + lane];
        pidx[lane] = pid;
        const float* vp = verts + (size_t)pid * 3;
        float x = vp[0], y = vp[1], z = vp[2];
        cst[lane*4+0] = x; cst[lane*4+1] = y; cst[lane*4+2] = z;
        uint4 cw;
        cw.x = (unsigned)f2bf(x) | ((unsigned)f2bf(y) << 16);
        cw.y = (unsigned)f2bf(z);
        cw.z = 0u; cw.w = 0u;
        *(uint4*)(stage + lane * 104 + 64) = cw;
    }
    __syncthreads();

    // ---- sample column 0 (lane = channel; coords from cst broadcast) ----
#pragma unroll 4
    for (int p = 0; p < PT; ++p) {
        float s = sample_tr(xtb, lane, cst[p*4], cst[p*4+1], cst[p*4+2]);
        stage[p * 104 + lane] = f2bf(s);
    }
    __syncthreads();

    // ---- merged GEMM pass: ph + nh1(col0) + delta(hi+lo), K=96 ----
    f32x4 pf[4], nf[4], hh[4], dd[2];
#pragma unroll
    for (int n = 0; n < 4; ++n) {
        pf[n] = (f32x4){bias_p[n], bias_p[n], bias_p[n], bias_p[n]};
        hh[n] = (f32x4){bias_h[n], bias_h[n], bias_h[n], bias_h[n]};
        nf[n] = (f32x4){0.f, 0.f, 0.f, 0.f};
    }
#pragma unroll
    for (int n = 0; n < 2; ++n) dd[n] = (f32x4){bias_d[n], bias_d[n], bias_d[n], bias_d[n]};

    __builtin_amdgcn_s_setprio(1);
#pragma unroll
    for (int kt = 0; kt < 3; ++kt) {
        bf16x8 a = *(const bf16x8*)(stage + l15 * 104 + kt * 32 + lg * 8);
#pragma unroll
        for (int n = 0; n < 4; ++n) {
            bf16x8 bw = *(const bf16x8*)(Wph + ((kt*4 + n) << 9) + lane * 8);
            pf[n] = __builtin_amdgcn_mfma_f32_16x16x32_bf16(a, bw, pf[n], 0, 0, 0);
            bf16x8 b1 = *(const bf16x8*)(Wn1 + ((kt*4 + n) << 9) + lane * 8);
            hh[n] = __builtin_amdgcn_mfma_f32_16x16x32_bf16(a, b1, hh[n], 0, 0, 0);
        }
#pragma unroll
        for (int n = 0; n < 2; ++n) {
            bf16x8 bh = *(const bf16x8*)(Wdh + ((kt*2 + n) << 9) + lane * 8);
            dd[n] = __builtin_amdgcn_mfma_f32_16x16x32_bf16(a, bh, dd[n], 0, 0, 0);
            bf16x8 bl = *(const bf16x8*)(Wdl + ((kt*2 + n) << 9) + lane * 8);
            dd[n] = __builtin_amdgcn_mfma_f32_16x16x32_bf16(a, bl, dd[n], 0, 0, 0);
        }
    }
    __builtin_amdgcn_s_setprio(0);

    // D layout: row=(lg*4+r) [point], col=n*16+l15
#pragma unroll
    for (int n = 0; n < 2; ++n)
#pragma unroll
        for (int r = 0; r < 4; ++r)
            dls[(lg*4 + r) * 32 + n*16 + l15] = dd[n][r];
#pragma unroll
    for (int n = 0; n < 4; ++n)
#pragma unroll
        for (int r = 0; r < 4; ++r)
            hst[(lg*4 + r) * 72 + n*16 + l15] = f2bf(gelu_exact(hh[n][r]));
    __syncthreads();

    // ---- nh2 column 0 (K=64, 2 ksteps) ----
    __builtin_amdgcn_s_setprio(1);
#pragma unroll
    for (int kt = 0; kt < 2; ++kt) {
        bf16x8 a = *(const bf16x8*)(hst + l15 * 72 + kt * 32 + lg * 8);
#pragma unroll
        for (int n = 0; n < 4; ++n) {
            bf16x8 bw = *(const bf16x8*)(Wn2 + ((kt*4 + n) << 9) + lane * 8);
            nf[n] = __builtin_amdgcn_mfma_f32_16x16x32_bf16(a, bw, nf[n], 0, 0, 0);
        }
    }
    __builtin_amdgcn_s_setprio(0);

    // ---- neighbour columns 1..8 ----
    for (int k = 0; k < Kc; ++k) {
        if (lane < PT) {
            float x = cst[lane*4+0] + dls[lane*32 + 3*k + 0];
            float y = cst[lane*4+1] + dls[lane*32 + 3*k + 1];
            float z = cst[lane*4+2] + dls[lane*32 + 3*k + 2];
            uint4 cw;
            cw.x = (unsigned)f2bf(x) | ((unsigned)f2bf(y) << 16);
            cw.y = (unsigned)f2bf(z);
            cw.z = 0u; cw.w = 0u;
            *(uint4*)(stage + lane * 104 + 64) = cw;
        }
#pragma unroll 4
        for (int p = 0; p < PT; ++p) {
            float nx = cst[p*4+0] + dls[p*32 + 3*k + 0];
            float ny = cst[p*4+1] + dls[p*32 + 3*k + 1];
            float nz = cst[p*4+2] + dls[p*32 + 3*k + 2];
            float s = sample_tr(xtb, lane, nx, ny, nz);
            stage[p * 104 + lane] = f2bf(s);
        }
        __syncthreads();

        f32x4 hk[4];
#pragma unroll
        for (int n = 0; n < 4; ++n) hk[n] = (f32x4){bias_h[n], bias_h[n], bias_h[n], bias_h[n]};
        __builtin_amdgcn_s_setprio(1);
#pragma unroll
        for (int kt = 0; kt < 3; ++kt) {
            bf16x8 a = *(const bf16x8*)(stage + l15 * 104 + kt * 32 + lg * 8);
#pragma unroll
            for (int n = 0; n < 4; ++n) {
                bf16x8 b1 = *(const bf16x8*)(Wn1 + ((kt*4 + n) << 9) + lane * 8);
                hk[n] = __builtin_amdgcn_mfma_f32_16x16x32_bf16(a, b1, hk[n], 0, 0, 0);
            }
        }
        __builtin_amdgcn_s_setprio(0);
#pragma unroll
        for (int n = 0; n < 4; ++n)
#pragma unroll
            for (int r = 0; r < 4; ++r)
                hst[(lg*4 + r) * 72 + n*16 + l15] = f2bf(gelu_exact(hk[n][r]));
        __syncthreads();

        const ushort* Wk = Wn2 + ((size_t)(k + 1) << 12);
        __builtin_amdgcn_s_setprio(1);
#pragma unroll
        for (int kt = 0; kt < 2; ++kt) {
            bf16x8 a = *(const bf16x8*)(hst + l15 * 72 + kt * 32 + lg * 8);
#pragma unroll
            for (int n = 0; n < 4; ++n) {
                bf16x8 bw = *(const bf16x8*)(Wk + ((kt*4 + n) << 9) + lane * 8);
                nf[n] = __builtin_amdgcn_mfma_f32_16x16x32_bf16(a, bw, nf[n], 0, 0, 0);
            }
        }
        __builtin_amdgcn_s_setprio(0);
    }

    // ---- store out[pid][channel] = pf + nf (scattered rows via perm) ----
#pragma unroll
    for (int r = 0; r < 4; ++r) {
        size_t row = (size_t)pidx[lg*4 + r] * 64;
#pragma unroll
        for (int n = 0; n < 4; ++n)
            out[row + n*16 + l15] = pf[n][r] + nf[n][r];
    }
}

// ---------------- correctness fallback (only if ws too small; slow, f32) ----------------
__global__ __launch_bounds__(64) void sb_fallback(
        const float* __restrict__ x, const float* __restrict__ verts,
        const float* __restrict__ shape_w, const float* __restrict__ shape_b,
        const float* __restrict__ delta_w, const float* __restrict__ delta_b,
        const float* __restrict__ ph_w, const float* __restrict__ ph_b,
        const float* __restrict__ nh1_w, const float* __restrict__ nh1_b,
        const float* __restrict__ nh2_w, float* __restrict__ out) {
    __shared__ float cp[72];
    __shared__ float hcol[64];
    __shared__ float dl[24];
    int lane = threadIdx.x;
    int g = blockIdx.x;
    int b = g / Nc;
    const float* xb = x + ((size_t)(b * 64 + lane) << 18);
    float vx = verts[g*3], vy = verts[g*3+1], vz = verts[g*3+2];
    cp[lane] = sample_cm(xb, vx, vy, vz);
    if (lane < 8) {
        float v = 0.0f;
        if      (lane == 0) v = vx;
        else if (lane == 1) v = vy;
        else if (lane == 2) v = vz;
        else if (lane < 7) {
            int i = lane - 3;
            v = 64.0f*(shape_w[i*4]+shape_w[i*4+1]+shape_w[i*4+2]+shape_w[i*4+3]) + shape_b[i];
        }
        cp[64 + lane] = v;
    }
    __syncthreads();
    float pfv = ph_b[lane];
    for (int j = 0; j < 67; ++j) pfv += ph_w[lane*67 + j] * cp[j];
    if (lane < 24) {
        float s = delta_b[lane];
        for (int j = 0; j < 71; ++j) s += delta_w[lane*71 + j] * cp[j];
        dl[lane] = s;
    }
    float h = nh1_b[lane];
    for (int j = 0; j < 67; ++j) h += nh1_w[lane*67 + j] * cp[j];
    hcol[lane] = gelu_exact(h);
    __syncthreads();
    float nfv = 0.0f;
    for (int c2 = 0; c2 < 64; ++c2) nfv += nh2_w[(lane*64 + c2)*9] * hcol[c2];
    for (int k = 0; k < 8; ++k) {
        __syncthreads();
        float nx = vx + dl[3*k], ny = vy + dl[3*k+1], nz = vz + dl[3*k+2];
        cp[lane] = sample_cm(xb, nx, ny, nz);
        if (lane < 3) cp[64 + lane] = (lane == 0) ? nx : (lane == 1) ? ny : nz;
        __syncthreads();
        float hv = nh1_b[lane];
        for (int j = 0; j < 67; ++j) hv += nh1_w[lane*67 + j] * cp[j];
        hcol[lane] = gelu_exact(hv);
        __syncthreads();
        for (int c2 = 0; c2 < 64; ++c2) nfv += nh2_w[(lane*64 + c2)*9 + k + 1] * hcol[c2];
    }
    out[(size_t)g * 64 + lane] = pfv + nfv;
}

// ---------------- launch ----------------
extern "C" void kernel_launch(void* const* d_in, const int* in_sizes, int n_in,
                              void* d_out, int out_size, void* d_ws, size_t ws_size,
                              hipStream_t stream) {
    const float* x       = (const float*)d_in[0];
    const float* verts   = (const float*)d_in[1];
    const float* shape_w = (const float*)d_in[2];
    const float* shape_b = (const float*)d_in[3];
    const float* delta_w = (const float*)d_in[4];
    const float* delta_b = (const float*)d_in[5];
    const float* ph_w    = (const float*)d_in[6];
    const float* ph_b    = (const float*)d_in[7];
    const float* nh1_w   = (const float*)d_in[8];
    const float* nh1_b   = (const float*)d_in[9];
    const float* nh2_w   = (const float*)d_in[10];
    float* out = (float*)d_out;
    char*  wsb = (char*)d_ws;

    if (ws_size >= WS_NEED) {
        ushort* xt  = (ushort*)(wsb + XT_BYTE);
        int* hist   = (int*)(wsb + HIST_OFF);
        int* perm   = (int*)(wsb + PERM_OFF);
        sb_pack<<<96, 256, 0, stream>>>(shape_w, shape_b, delta_w, delta_b,
                                        ph_w, ph_b, nh1_w, nh1_b, nh2_w, wsb);
        sb_transpose<<<Bc * 4096, 256, 0, stream>>>(x, xt);
        sb_zero<<<(NBINS + 255) / 256, 256, 0, stream>>>(hist);
        sb_hist<<<(NPTS + 255) / 256, 256, 0, stream>>>(verts, hist);
        sb_scan<<<1, 1024, 0, stream>>>(hist);
        sb_scatter<<<(NPTS + 255) / 256, 256, 0, stream>>>(verts, hist, perm);
        sb_main_mfma<<<NBLK, 64, 0, stream>>>(xt, verts, perm, wsb, out);
    } else {
        sb_fallback<<<Bc * Nc, 64, 0, stream>>>(x, verts, shape_w, shape_b, delta_w, delta_b,
                                                ph_w, ph_b, nh1_w, nh1_b, nh2_w, out);
    }
}

// Round 12
// 336.923 us; speedup vs baseline: 1.8619x; 1.8619x over previous
//
#include <hip/hip_runtime.h>
#include <math.h>

// ---------------- problem constants ----------------
constexpr int Bc = 2, Cc = 64, Nc = 50000, Kc = 8;
constexpr int PT = 16;                       // points per wave (MFMA M dim)
constexpr int NBLK = (Bc * Nc) / PT;         // 6250, exact

// ---------------- ws byte layout (same as round 8) ----------------
constexpr int BIAS_PH = 16;                  // f32[64]
constexpr int BIAS_N1 = 272;                 // f32[64]
constexpr int BIAS_DL = 528;                 // f32[32] (sv folded, padded)
constexpr int B_PH  = 1024;                  // 12 frags * 1KB
constexpr int B_N1  = 13312;                 // 12 frags
constexpr int B_DH  = 25600;                 // 6 frags (delta hi)
constexpr int B_DLO = 31744;                 // 6 frags (delta lo)
constexpr int B_N2  = 37888;                 // 72 frags -> ends 111616
constexpr size_t XT_BYTE = 262144;           // bf16 volume starts here
constexpr size_t XT_USHORTS = (size_t)Bc * 64 * 64 * 64 * 64;

using bf16x8 = __attribute__((ext_vector_type(8))) short;
using f32x4  = __attribute__((ext_vector_type(4))) float;

// ---------------- helpers ----------------
__device__ __forceinline__ float gelu_exact(float v) {
    return 0.5f * v * (1.0f + erff(v * 0.70710678118654752f));
}
__device__ __forceinline__ ushort f2bf(float f) {           // RNE f32 -> bf16 bits
    unsigned u = __float_as_uint(f);
    unsigned r = (u + 0x7FFFu + ((u >> 16) & 1u)) >> 16;
    return (ushort)r;
}
__device__ __forceinline__ float bf2f(ushort u) {
    return __uint_as_float(((unsigned)u) << 16);
}
__device__ __forceinline__ float tri8(float v000, float v001, float v010, float v011,
                                      float v100, float v101, float v110, float v111,
                                      float fx, float fy, float fz) {
    float c00 = fmaf(fx, v001 - v000, v000);
    float c01 = fmaf(fx, v011 - v010, v010);
    float c10 = fmaf(fx, v101 - v100, v100);
    float c11 = fmaf(fx, v111 - v110, v110);
    float c0  = fmaf(fy, c01 - c00, c00);
    float c1  = fmaf(fy, c11 - c10, c10);
    return fmaf(fz, c1 - c0, c0);
}

// half-wave dword-pair sampling: lane handles channels (2cp, 2cp+1) of point p.
// 8 dword gathers (each: half-wave covers one full 64-ch corner line = 128B).
__device__ __forceinline__ void sample_pair(const unsigned* __restrict__ xtb32,
                                            ushort* __restrict__ stage,
                                            int cp, int p,
                                            float nx, float ny, float nz) {
    float ix = fminf(fmaxf((nx + 1.0f) * 31.5f, 0.0f), 63.0f);
    float iy = fminf(fmaxf((ny + 1.0f) * 31.5f, 0.0f), 63.0f);
    float iz = fminf(fmaxf((nz + 1.0f) * 31.5f, 0.0f), 63.0f);
    float fx0 = floorf(ix), fy0 = floorf(iy), fz0 = floorf(iz);
    int x0 = (int)fx0, y0 = (int)fy0, z0 = (int)fz0;
    float fx = ix - fx0, fy = iy - fy0, fz = iz - fz0;
    int dx = (x0 < 63) ? 32 : 0;          // +1 in x = +32 dwords (64 ushorts)
    int dy = (y0 < 63) ? 2048 : 0;        // +1 in y
    int dz = (z0 < 63) ? 131072 : 0;      // +1 in z
    const unsigned* r = xtb32 + ((((z0 << 12) + (y0 << 6) + x0) << 5) + cp);
    unsigned u000 = r[0],       u001 = r[dx];
    unsigned u010 = r[dy],      u011 = r[dy + dx];
    unsigned u100 = r[dz],      u101 = r[dz + dx];
    unsigned u110 = r[dz + dy], u111 = r[dz + dy + dx];
    float sa = tri8(bf2f((ushort)u000), bf2f((ushort)u001),
                    bf2f((ushort)u010), bf2f((ushort)u011),
                    bf2f((ushort)u100), bf2f((ushort)u101),
                    bf2f((ushort)u110), bf2f((ushort)u111), fx, fy, fz);
    float sb = tri8(bf2f((ushort)(u000 >> 16)), bf2f((ushort)(u001 >> 16)),
                    bf2f((ushort)(u010 >> 16)), bf2f((ushort)(u011 >> 16)),
                    bf2f((ushort)(u100 >> 16)), bf2f((ushort)(u101 >> 16)),
                    bf2f((ushort)(u110 >> 16)), bf2f((ushort)(u111 >> 16)), fx, fy, fz);
    *(unsigned*)(stage + p * 104 + 2 * cp) =
        (unsigned)f2bf(sa) | ((unsigned)f2bf(sb) << 16);
}

// ---- fallback (channel-major f32) sampling ----
__device__ __forceinline__ float sample_cm(const float* __restrict__ xb,
                                           float gx, float gy, float gz) {
    float ix = fminf(fmaxf((gx + 1.0f) * 31.5f, 0.0f), 63.0f);
    float iy = fminf(fmaxf((gy + 1.0f) * 31.5f, 0.0f), 63.0f);
    float iz = fminf(fmaxf((gz + 1.0f) * 31.5f, 0.0f), 63.0f);
    float fx0 = floorf(ix), fy0 = floorf(iy), fz0 = floorf(iz);
    int x0 = (int)fx0, y0 = (int)fy0, z0 = (int)fz0;
    float fx = ix - fx0, fy = iy - fy0, fz = iz - fz0;
    int x1 = (x0 < 63) ? x0 + 1 : 63;
    int dy = (y0 < 63) ? 64 : 0;
    int dz = (z0 < 63) ? 4096 : 0;
    const float* r = xb + ((z0 << 12) + (y0 << 6));
    float v000 = r[x0],           v001 = r[x1];
    float v010 = r[x0 + dy],      v011 = r[x1 + dy];
    float v100 = r[x0 + dz],      v101 = r[x1 + dz];
    float v110 = r[x0 + dy + dz], v111 = r[x1 + dy + dz];
    return tri8(v000, v001, v010, v011, v100, v101, v110, v111, fx, fy, fz);
}

// ---------------- weight packing: B-fragment lane order, bf16 (unchanged) ----------------
__global__ void sb_pack(const float* __restrict__ shape_w, const float* __restrict__ shape_b,
                        const float* __restrict__ delta_w, const float* __restrict__ delta_b,
                        const float* __restrict__ ph_w, const float* __restrict__ ph_b,
                        const float* __restrict__ nh1_w, const float* __restrict__ nh1_b,
                        const float* __restrict__ nh2_w, char* __restrict__ wsb) {
    int tid = blockIdx.x * blockDim.x + threadIdx.x;
    int nt  = gridDim.x * blockDim.x;
    float*  bph = (float*)(wsb + BIAS_PH);
    float*  bn1 = (float*)(wsb + BIAS_N1);
    float*  bdl = (float*)(wsb + BIAS_DL);
    ushort* wph = (ushort*)(wsb + B_PH);
    ushort* wn1 = (ushort*)(wsb + B_N1);
    ushort* wdh = (ushort*)(wsb + B_DH);
    ushort* wdl = (ushort*)(wsb + B_DLO);
    ushort* wn2 = (ushort*)(wsb + B_N2);

    for (int e = tid; e < 64; e += nt) { bph[e] = ph_b[e]; bn1[e] = nh1_b[e]; }
    for (int e = tid; e < 32; e += nt) {
        float v = 0.0f;
        if (e < 24) {
            v = delta_b[e];
#pragma unroll
            for (int i = 0; i < 4; ++i) {   // fold shape_vec (constant) into bias, f32 exact
                float sv = 64.0f * (shape_w[i*4] + shape_w[i*4+1] + shape_w[i*4+2] + shape_w[i*4+3])
                         + shape_b[i];
                v += sv * delta_w[e * 71 + 67 + i];
            }
        }
        bdl[e] = v;
    }
    for (int e = tid; e < 6144; e += nt) {
        int frag = e >> 9, lane = (e >> 3) & 63, j = e & 7;
        int kt = frag >> 2, n = frag & 3;
        int k = kt * 32 + ((lane >> 4) << 3) + j;
        int col = n * 16 + (lane & 15);
        wph[e] = (k < 67) ? f2bf(ph_w[col * 67 + k])  : (ushort)0;
        wn1[e] = (k < 67) ? f2bf(nh1_w[col * 67 + k]) : (ushort)0;
    }
    for (int e = tid; e < 3072; e += nt) {
        int frag = e >> 9, lane = (e >> 3) & 63, j = e & 7;
        int kt = frag >> 1, n = frag & 1;
        int k = kt * 32 + ((lane >> 4) << 3) + j;
        int col = n * 16 + (lane & 15);
        float w = (col < 24 && k < 67) ? delta_w[col * 71 + k] : 0.0f;
        ushort hi = f2bf(w);
        wdh[e] = hi;
        wdl[e] = f2bf(w - bf2f(hi));
    }
    for (int e = tid; e < 36864; e += nt) {
        int frag = e >> 9, lane = (e >> 3) & 63, j = e & 7;
        int c9 = frag >> 3, kt = (frag >> 2) & 1, n = frag & 3;
        int k = kt * 32 + ((lane >> 4) << 3) + j;
        int c = n * 16 + (lane & 15);
        wn2[e] = f2bf(nh2_w[(c * 64 + k) * 9 + c9]);
    }
}

// ---------------- transpose x [B,C,64^3] f32 -> xt [B,64^3,C] bf16 (unchanged) ----------------
__global__ __launch_bounds__(256) void sb_transpose(const float* __restrict__ x,
                                                    ushort* __restrict__ xt) {
    __shared__ float tile[64][65];
    int blk = blockIdx.x;
    int b = blk >> 12, zy = blk & 4095;
    const float* __restrict__ src = x + ((size_t)b << 24) + zy * 64;
    unsigned* __restrict__ dst32 = (unsigned*)(xt + ((size_t)b << 24) + (size_t)zy * 4096);
    int t = threadIdx.x;
    int xx = t & 63, c0 = t >> 6;
#pragma unroll
    for (int i = 0; i < 16; ++i) {
        int c = i * 4 + c0;
        tile[c][xx] = src[((size_t)c << 18) + xx];
    }
    __syncthreads();
    int cp = t & 31, xs0 = t >> 5;
#pragma unroll
    for (int i = 0; i < 8; ++i) {
        int xs = i * 8 + xs0;
        unsigned lo = f2bf(tile[cp * 2][xs]);
        unsigned hi = f2bf(tile[cp * 2 + 1][xs]);
        dst32[xs * 32 + cp] = lo | (hi << 16);
    }
}

// ---------------- main MFMA kernel: 1 wave = 16 points, dword-pair gathers ----------------
__global__ __launch_bounds__(64) void sb_main_mfma(
        const ushort* __restrict__ xt, const float* __restrict__ verts,
        const char* __restrict__ wsb, float* __restrict__ out) {
    __shared__ __align__(16) ushort stage[PT * 104];  // A tile [point][K..95], pad stride 104
    __shared__ __align__(16) ushort hst[PT * 72];     // gelu(h) A tile
    __shared__ float cst[PT * 4];                     // vertex coords
    __shared__ float dls[PT * 32];                    // delta outputs

    const int lane = threadIdx.x;
    const int l15 = lane & 15, lg = lane >> 4;
    const int half8 = (lane >> 5) * 8;                // sampling: point offset for this half-wave
    const int cp = lane & 31;                         // sampling: channel pair
    const int g0 = blockIdx.x * PT;
    const int b  = g0 / Nc;
    const unsigned* __restrict__ xtb32 = (const unsigned*)(xt + ((size_t)b << 24));

    const float*  bph = (const float*)(wsb + BIAS_PH);
    const float*  bn1 = (const float*)(wsb + BIAS_N1);
    const float*  bdl = (const float*)(wsb + BIAS_DL);
    const ushort* Wph = (const ushort*)(wsb + B_PH);
    const ushort* Wn1 = (const ushort*)(wsb + B_N1);
    const ushort* Wdh = (const ushort*)(wsb + B_DH);
    const ushort* Wdl = (const ushort*)(wsb + B_DLO);
    const ushort* Wn2 = (const ushort*)(wsb + B_N2);

    // zero-init A tile (pad cols 72..103 are MFMA-read vs zero weights; NaN*0=NaN otherwise)
#pragma unroll
    for (int i = 0; i < (PT * 104) / 64; ++i) stage[i * 64 + lane] = 0;

    float bias_p[4], bias_h[4], bias_d[2];
#pragma unroll
    for (int n = 0; n < 4; ++n) { bias_p[n] = bph[n*16 + l15]; bias_h[n] = bn1[n*16 + l15]; }
#pragma unroll
    for (int n = 0; n < 2; ++n) bias_d[n] = bdl[n*16 + l15];

    // init: verts -> cst + stage coord block (cols 64..71; 67.. zero, weights zero-padded)
    if (lane < PT) {
        const float* vp = verts + (size_t)(g0 + lane) * 3;
        float x = vp[0], y = vp[1], z = vp[2];
        cst[lane*4+0] = x; cst[lane*4+1] = y; cst[lane*4+2] = z;
        uint4 cw;
        cw.x = (unsigned)f2bf(x) | ((unsigned)f2bf(y) << 16);
        cw.y = (unsigned)f2bf(z);
        cw.z = 0u; cw.w = 0u;
        *(uint4*)(stage + lane * 104 + 64) = cw;
    }
    __syncthreads();

    // ---- sample column 0: half-wave point split, 64 dword gathers ----
#pragma unroll 4
    for (int pp = 0; pp < 8; ++pp) {
        int p = half8 + pp;
        sample_pair(xtb32, stage, cp, p, cst[p*4+0], cst[p*4+1], cst[p*4+2]);
    }
    __syncthreads();

    // ---- merged GEMM pass: ph + nh1(col0) + delta(hi+lo), K=96 ----
    f32x4 pf[4], nf[4], hh[4], dd[2];
#pragma unroll
    for (int n = 0; n < 4; ++n) {
        pf[n] = (f32x4){bias_p[n], bias_p[n], bias_p[n], bias_p[n]};
        hh[n] = (f32x4){bias_h[n], bias_h[n], bias_h[n], bias_h[n]};
        nf[n] = (f32x4){0.f, 0.f, 0.f, 0.f};
    }
#pragma unroll
    for (int n = 0; n < 2; ++n) dd[n] = (f32x4){bias_d[n], bias_d[n], bias_d[n], bias_d[n]};

#pragma unroll
    for (int kt = 0; kt < 3; ++kt) {
        bf16x8 a = *(const bf16x8*)(stage + l15 * 104 + kt * 32 + lg * 8);
#pragma unroll
        for (int n = 0; n < 4; ++n) {
            bf16x8 bw = *(const bf16x8*)(Wph + ((kt*4 + n) << 9) + lane * 8);
            pf[n] = __builtin_amdgcn_mfma_f32_16x16x32_bf16(a, bw, pf[n], 0, 0, 0);
            bf16x8 b1 = *(const bf16x8*)(Wn1 + ((kt*4 + n) << 9) + lane * 8);
            hh[n] = __builtin_amdgcn_mfma_f32_16x16x32_bf16(a, b1, hh[n], 0, 0, 0);
        }
#pragma unroll
        for (int n = 0; n < 2; ++n) {
            bf16x8 bh = *(const bf16x8*)(Wdh + ((kt*2 + n) << 9) + lane * 8);
            dd[n] = __builtin_amdgcn_mfma_f32_16x16x32_bf16(a, bh, dd[n], 0, 0, 0);
            bf16x8 bl = *(const bf16x8*)(Wdl + ((kt*2 + n) << 9) + lane * 8);
            dd[n] = __builtin_amdgcn_mfma_f32_16x16x32_bf16(a, bl, dd[n], 0, 0, 0);
        }
    }

    // D layout: row=(lg*4+r) [point], col=n*16+l15
#pragma unroll
    for (int n = 0; n < 2; ++n)
#pragma unroll
        for (int r = 0; r < 4; ++r)
            dls[(lg*4 + r) * 32 + n*16 + l15] = dd[n][r];
#pragma unroll
    for (int n = 0; n < 4; ++n)
#pragma unroll
        for (int r = 0; r < 4; ++r)
            hst[(lg*4 + r) * 72 + n*16 + l15] = f2bf(gelu_exact(hh[n][r]));
    __syncthreads();

    // ---- nh2 column 0 (K=64, 2 ksteps) ----
#pragma unroll
    for (int kt = 0; kt < 2; ++kt) {
        bf16x8 a = *(const bf16x8*)(hst + l15 * 72 + kt * 32 + lg * 8);
#pragma unroll
        for (int n = 0; n < 4; ++n) {
            bf16x8 bw = *(const bf16x8*)(Wn2 + ((kt*4 + n) << 9) + lane * 8);
            nf[n] = __builtin_amdgcn_mfma_f32_16x16x32_bf16(a, bw, nf[n], 0, 0, 0);
        }
    }

    // ---- neighbour columns 1..8 ----
    for (int k = 0; k < Kc; ++k) {
        // coord block cols 64..71 for this column
        if (lane < PT) {
            float x = cst[lane*4+0] + dls[lane*32 + 3*k + 0];
            float y = cst[lane*4+1] + dls[lane*32 + 3*k + 1];
            float z = cst[lane*4+2] + dls[lane*32 + 3*k + 2];
            uint4 cw;
            cw.x = (unsigned)f2bf(x) | ((unsigned)f2bf(y) << 16);
            cw.y = (unsigned)f2bf(z);
            cw.z = 0u; cw.w = 0u;
            *(uint4*)(stage + lane * 104 + 64) = cw;
        }
        // sample: half-wave point split, coords recomputed per lane (LDS broadcast)
#pragma unroll 4
        for (int pp = 0; pp < 8; ++pp) {
            int p = half8 + pp;
            float nx = cst[p*4+0] + dls[p*32 + 3*k + 0];
            float ny = cst[p*4+1] + dls[p*32 + 3*k + 1];
            float nz = cst[p*4+2] + dls[p*32 + 3*k + 2];
            sample_pair(xtb32, stage, cp, p, nx, ny, nz);
        }
        __syncthreads();

        f32x4 hk[4];
#pragma unroll
        for (int n = 0; n < 4; ++n) hk[n] = (f32x4){bias_h[n], bias_h[n], bias_h[n], bias_h[n]};
#pragma unroll
        for (int kt = 0; kt < 3; ++kt) {
            bf16x8 a = *(const bf16x8*)(stage + l15 * 104 + kt * 32 + lg * 8);
#pragma unroll
            for (int n = 0; n < 4; ++n) {
                bf16x8 b1 = *(const bf16x8*)(Wn1 + ((kt*4 + n) << 9) + lane * 8);
                hk[n] = __builtin_amdgcn_mfma_f32_16x16x32_bf16(a, b1, hk[n], 0, 0, 0);
            }
        }
#pragma unroll
        for (int n = 0; n < 4; ++n)
#pragma unroll
            for (int r = 0; r < 4; ++r)
                hst[(lg*4 + r) * 72 + n*16 + l15] = f2bf(gelu_exact(hk[n][r]));
        __syncthreads();

        const ushort* Wk = Wn2 + ((size_t)(k + 1) << 12);
#pragma unroll
        for (int kt = 0; kt < 2; ++kt) {
            bf16x8 a = *(const bf16x8*)(hst + l15 * 72 + kt * 32 + lg * 8);
#pragma unroll
            for (int n = 0; n < 4; ++n) {
                bf16x8 bw = *(const bf16x8*)(Wk + ((kt*4 + n) << 9) + lane * 8);
                nf[n] = __builtin_amdgcn_mfma_f32_16x16x32_bf16(a, bw, nf[n], 0, 0, 0);
            }
        }
    }

    // ---- store out[point][channel] = pf + nf (contiguous rows) ----
#pragma unroll
    for (int n = 0; n < 4; ++n)
#pragma unroll
        for (int r = 0; r < 4; ++r)
            out[(size_t)(g0 + lg*4 + r) * 64 + n*16 + l15] = pf[n][r] + nf[n][r];
}

// ---------------- correctness fallback (only if ws too small; slow, f32) ----------------
__global__ __launch_bounds__(64) void sb_fallback(
        const float* __restrict__ x, const float* __restrict__ verts,
        const float* __restrict__ shape_w, const float* __restrict__ shape_b,
        const float* __restrict__ delta_w, const float* __restrict__ delta_b,
        const float* __restrict__ ph_w, const float* __restrict__ ph_b,
        const float* __restrict__ nh1_w, const float* __restrict__ nh1_b,
        const float* __restrict__ nh2_w, float* __restrict__ out) {
    __shared__ float cp[72];
    __shared__ float hcol[64];
    __shared__ float dl[24];
    int lane = threadIdx.x;
    int g = blockIdx.x;
    int b = g / Nc;
    const float* xb = x + ((size_t)(b * 64 + lane) << 18);
    float vx = verts[g*3], vy = verts[g*3+1], vz = verts[g*3+2];
    cp[lane] = sample_cm(xb, vx, vy, vz);
    if (lane < 8) {
        float v = 0.0f;
        if      (lane == 0) v = vx;
        else if (lane == 1) v = vy;
        else if (lane == 2) v = vz;
        else if (lane < 7) {
            int i = lane - 3;
            v = 64.0f*(shape_w[i*4]+shape_w[i*4+1]+shape_w[i*4+2]+shape_w[i*4+3]) + shape_b[i];
        }
        cp[64 + lane] = v;
    }
    __syncthreads();
    float pfv = ph_b[lane];
    for (int j = 0; j < 67; ++j) pfv += ph_w[lane*67 + j] * cp[j];
    if (lane < 24) {
        float s = delta_b[lane];
        for (int j = 0; j < 71; ++j) s += delta_w[lane*71 + j] * cp[j];
        dl[lane] = s;
    }
    float h = nh1_b[lane];
    for (int j = 0; j < 67; ++j) h += nh1_w[lane*67 + j] * cp[j];
    hcol[lane] = gelu_exact(h);
    __syncthreads();
    float nfv = 0.0f;
    for (int c2 = 0; c2 < 64; ++c2) nfv += nh2_w[(lane*64 + c2)*9] * hcol[c2];
    for (int k = 0; k < 8; ++k) {
        __syncthreads();
        float nx = vx + dl[3*k], ny = vy + dl[3*k+1], nz = vz + dl[3*k+2];
        cp[lane] = sample_cm(xb, nx, ny, nz);
        if (lane < 3) cp[64 + lane] = (lane == 0) ? nx : (lane == 1) ? ny : nz;
        __syncthreads();
        float hv = nh1_b[lane];
        for (int j = 0; j < 67; ++j) hv += nh1_w[lane*67 + j] * cp[j];
        hcol[lane] = gelu_exact(hv);
        __syncthreads();
        for (int c2 = 0; c2 < 64; ++c2) nfv += nh2_w[(lane*64 + c2)*9 + k + 1] * hcol[c2];
    }
    out[(size_t)g * 64 + lane] = pfv + nfv;
}

// ---------------- launch ----------------
extern "C" void kernel_launch(void* const* d_in, const int* in_sizes, int n_in,
                              void* d_out, int out_size, void* d_ws, size_t ws_size,
                              hipStream_t stream) {
    const float* x       = (const float*)d_in[0];
    const float* verts   = (const float*)d_in[1];
    const float* shape_w = (const float*)d_in[2];
    const float* shape_b = (const float*)d_in[3];
    const float* delta_w = (const float*)d_in[4];
    const float* delta_b = (const float*)d_in[5];
    const float* ph_w    = (const float*)d_in[6];
    const float* ph_b    = (const float*)d_in[7];
    const float* nh1_w   = (const float*)d_in[8];
    const float* nh1_b   = (const float*)d_in[9];
    const float* nh2_w   = (const float*)d_in[10];
    float* out = (float*)d_out;
    char*  wsb = (char*)d_ws;

    const size_t need = XT_BYTE + XT_USHORTS * 2;
    if (ws_size >= need) {
        ushort* xt = (ushort*)(wsb + XT_BYTE);
        sb_pack<<<96, 256, 0, stream>>>(shape_w, shape_b, delta_w, delta_b,
                                        ph_w, ph_b, nh1_w, nh1_b, nh2_w, wsb);
        sb_transpose<<<Bc * 4096, 256, 0, stream>>>(x, xt);
        sb_main_mfma<<<NBLK, 64, 0, stream>>>(xt, verts, wsb, out);
    } else {
        sb_fallback<<<Bc * Nc, 64, 0, stream>>>(x, verts, shape_w, shape_b, delta_w, delta_b,
                                                ph_w, ph_b, nh1_w, nh1_b, nh2_w, out);
    }
}

// Round 13
// 286.093 us; speedup vs baseline: 2.1927x; 1.1777x over previous
//
#include <hip/hip_runtime.h>
#include <math.h>

// ---------------- problem constants ----------------
constexpr int Bc = 2, Cc = 64, Nc = 50000, Kc = 8;
constexpr int PT = 16;                       // points per wave (MFMA M dim)
constexpr int NBLK = (Bc * Nc) / PT;         // 6250, exact

// ---------------- ws byte layout (same as round 8) ----------------
constexpr int BIAS_PH = 16;                  // f32[64]
constexpr int BIAS_N1 = 272;                 // f32[64]
constexpr int BIAS_DL = 528;                 // f32[32] (sv folded, padded)
constexpr int B_PH  = 1024;                  // 12 frags * 1KB
constexpr int B_N1  = 13312;                 // 12 frags
constexpr int B_DH  = 25600;                 // 6 frags (delta hi)
constexpr int B_DLO = 31744;                 // 6 frags (delta lo)
constexpr int B_N2  = 37888;                 // 72 frags -> ends 111616
constexpr size_t XT_BYTE = 262144;           // bf16 volume starts here
constexpr size_t XT_USHORTS = (size_t)Bc * 64 * 64 * 64 * 64;

using bf16x8 = __attribute__((ext_vector_type(8))) short;
using f32x4  = __attribute__((ext_vector_type(4))) float;

// ---------------- helpers ----------------
__device__ __forceinline__ float gelu_exact(float v) {
    return 0.5f * v * (1.0f + erff(v * 0.70710678118654752f));
}
__device__ __forceinline__ ushort f2bf(float f) {           // RNE f32 -> bf16 bits
    unsigned u = __float_as_uint(f);
    unsigned r = (u + 0x7FFFu + ((u >> 16) & 1u)) >> 16;
    return (ushort)r;
}
__device__ __forceinline__ float bf2f(ushort u) {
    return __uint_as_float(((unsigned)u) << 16);
}
__device__ __forceinline__ float tri8(float v000, float v001, float v010, float v011,
                                      float v100, float v101, float v110, float v111,
                                      float fx, float fy, float fz) {
    float c00 = fmaf(fx, v001 - v000, v000);
    float c01 = fmaf(fx, v011 - v010, v010);
    float c10 = fmaf(fx, v101 - v100, v100);
    float c11 = fmaf(fx, v111 - v110, v110);
    float c0  = fmaf(fy, c01 - c00, c00);
    float c1  = fmaf(fy, c11 - c10, c10);
    return fmaf(fz, c1 - c0, c0);
}

// half-wave dword-pair sampling: lane handles channels (2cp, 2cp+1) of point p.
// 8 dword gathers (each: half-wave covers one full 64-ch corner line = 128B).
__device__ __forceinline__ void sample_pair(const unsigned* __restrict__ xtb32,
                                            ushort* __restrict__ stage,
                                            int cp, int p,
                                            float nx, float ny, float nz) {
    float ix = fminf(fmaxf((nx + 1.0f) * 31.5f, 0.0f), 63.0f);
    float iy = fminf(fmaxf((ny + 1.0f) * 31.5f, 0.0f), 63.0f);
    float iz = fminf(fmaxf((nz + 1.0f) * 31.5f, 0.0f), 63.0f);
    float fx0 = floorf(ix), fy0 = floorf(iy), fz0 = floorf(iz);
    int x0 = (int)fx0, y0 = (int)fy0, z0 = (int)fz0;
    float fx = ix - fx0, fy = iy - fy0, fz = iz - fz0;
    int dx = (x0 < 63) ? 32 : 0;          // +1 in x = +32 dwords (64 ushorts)
    int dy = (y0 < 63) ? 2048 : 0;        // +1 in y
    int dz = (z0 < 63) ? 131072 : 0;      // +1 in z
    const unsigned* r = xtb32 + ((((z0 << 12) + (y0 << 6) + x0) << 5) + cp);
    unsigned u000 = r[0],       u001 = r[dx];
    unsigned u010 = r[dy],      u011 = r[dy + dx];
    unsigned u100 = r[dz],      u101 = r[dz + dx];
    unsigned u110 = r[dz + dy], u111 = r[dz + dy + dx];
    float sa = tri8(bf2f((ushort)u000), bf2f((ushort)u001),
                    bf2f((ushort)u010), bf2f((ushort)u011),
                    bf2f((ushort)u100), bf2f((ushort)u101),
                    bf2f((ushort)u110), bf2f((ushort)u111), fx, fy, fz);
    float sb = tri8(bf2f((ushort)(u000 >> 16)), bf2f((ushort)(u001 >> 16)),
                    bf2f((ushort)(u010 >> 16)), bf2f((ushort)(u011 >> 16)),
                    bf2f((ushort)(u100 >> 16)), bf2f((ushort)(u101 >> 16)),
                    bf2f((ushort)(u110 >> 16)), bf2f((ushort)(u111 >> 16)), fx, fy, fz);
    *(unsigned*)(stage + p * 104 + 2 * cp) =
        (unsigned)f2bf(sa) | ((unsigned)f2bf(sb) << 16);
}

// ---- fallback (channel-major f32) sampling ----
__device__ __forceinline__ float sample_cm(const float* __restrict__ xb,
                                           float gx, float gy, float gz) {
    float ix = fminf(fmaxf((gx + 1.0f) * 31.5f, 0.0f), 63.0f);
    float iy = fminf(fmaxf((gy + 1.0f) * 31.5f, 0.0f), 63.0f);
    float iz = fminf(fmaxf((gz + 1.0f) * 31.5f, 0.0f), 63.0f);
    float fx0 = floorf(ix), fy0 = floorf(iy), fz0 = floorf(iz);
    int x0 = (int)fx0, y0 = (int)fy0, z0 = (int)fz0;
    float fx = ix - fx0, fy = iy - fy0, fz = iz - fz0;
    int x1 = (x0 < 63) ? x0 + 1 : 63;
    int dy = (y0 < 63) ? 64 : 0;
    int dz = (z0 < 63) ? 4096 : 0;
    const float* r = xb + ((z0 << 12) + (y0 << 6));
    float v000 = r[x0],           v001 = r[x1];
    float v010 = r[x0 + dy],      v011 = r[x1 + dy];
    float v100 = r[x0 + dz],      v101 = r[x1 + dz];
    float v110 = r[x0 + dy + dz], v111 = r[x1 + dy + dz];
    return tri8(v000, v001, v010, v011, v100, v101, v110, v111, fx, fy, fz);
}

// ---------------- weight packing: B-fragment lane order, bf16 (unchanged) ----------------
__global__ void sb_pack(const float* __restrict__ shape_w, const float* __restrict__ shape_b,
                        const float* __restrict__ delta_w, const float* __restrict__ delta_b,
                        const float* __restrict__ ph_w, const float* __restrict__ ph_b,
                        const float* __restrict__ nh1_w, const float* __restrict__ nh1_b,
                        const float* __restrict__ nh2_w, char* __restrict__ wsb) {
    int tid = blockIdx.x * blockDim.x + threadIdx.x;
    int nt  = gridDim.x * blockDim.x;
    float*  bph = (float*)(wsb + BIAS_PH);
    float*  bn1 = (float*)(wsb + BIAS_N1);
    float*  bdl = (float*)(wsb + BIAS_DL);
    ushort* wph = (ushort*)(wsb + B_PH);
    ushort* wn1 = (ushort*)(wsb + B_N1);
    ushort* wdh = (ushort*)(wsb + B_DH);
    ushort* wdl = (ushort*)(wsb + B_DLO);
    ushort* wn2 = (ushort*)(wsb + B_N2);

    for (int e = tid; e < 64; e += nt) { bph[e] = ph_b[e]; bn1[e] = nh1_b[e]; }
    for (int e = tid; e < 32; e += nt) {
        float v = 0.0f;
        if (e < 24) {
            v = delta_b[e];
#pragma unroll
            for (int i = 0; i < 4; ++i) {   // fold shape_vec (constant) into bias, f32 exact
                float sv = 64.0f * (shape_w[i*4] + shape_w[i*4+1] + shape_w[i*4+2] + shape_w[i*4+3])
                         + shape_b[i];
                v += sv * delta_w[e * 71 + 67 + i];
            }
        }
        bdl[e] = v;
    }
    for (int e = tid; e < 6144; e += nt) {
        int frag = e >> 9, lane = (e >> 3) & 63, j = e & 7;
        int kt = frag >> 2, n = frag & 3;
        int k = kt * 32 + ((lane >> 4) << 3) + j;
        int col = n * 16 + (lane & 15);
        wph[e] = (k < 67) ? f2bf(ph_w[col * 67 + k])  : (ushort)0;
        wn1[e] = (k < 67) ? f2bf(nh1_w[col * 67 + k]) : (ushort)0;
    }
    for (int e = tid; e < 3072; e += nt) {
        int frag = e >> 9, lane = (e >> 3) & 63, j = e & 7;
        int kt = frag >> 1, n = frag & 1;
        int k = kt * 32 + ((lane >> 4) << 3) + j;
        int col = n * 16 + (lane & 15);
        float w = (col < 24 && k < 67) ? delta_w[col * 71 + k] : 0.0f;
        ushort hi = f2bf(w);
        wdh[e] = hi;
        wdl[e] = f2bf(w - bf2f(hi));
    }
    for (int e = tid; e < 36864; e += nt) {
        int frag = e >> 9, lane = (e >> 3) & 63, j = e & 7;
        int c9 = frag >> 3, kt = (frag >> 2) & 1, n = frag & 3;
        int k = kt * 32 + ((lane >> 4) << 3) + j;
        int c = n * 16 + (lane & 15);
        wn2[e] = f2bf(nh2_w[(c * 64 + k) * 9 + c9]);
    }
}

// ---------------- transpose x [B,C,64^3] f32 -> xt [B,64^3,C] bf16 (unchanged) ----------------
__global__ __launch_bounds__(256) void sb_transpose(const float* __restrict__ x,
                                                    ushort* __restrict__ xt) {
    __shared__ float tile[64][65];
    int blk = blockIdx.x;
    int b = blk >> 12, zy = blk & 4095;
    const float* __restrict__ src = x + ((size_t)b << 24) + zy * 64;
    unsigned* __restrict__ dst32 = (unsigned*)(xt + ((size_t)b << 24) + (size_t)zy * 4096);
    int t = threadIdx.x;
    int xx = t & 63, c0 = t >> 6;
#pragma unroll
    for (int i = 0; i < 16; ++i) {
        int c = i * 4 + c0;
        tile[c][xx] = src[((size_t)c << 18) + xx];
    }
    __syncthreads();
    int cp = t & 31, xs0 = t >> 5;
#pragma unroll
    for (int i = 0; i < 8; ++i) {
        int xs = i * 8 + xs0;
        unsigned lo = f2bf(tile[cp * 2][xs]);
        unsigned hi = f2bf(tile[cp * 2 + 1][xs]);
        dst32[xs * 32 + cp] = lo | (hi << 16);
    }
}

// ---------------- main MFMA kernel: 1 wave = 16 points, dword-pair gathers ----------------
// __launch_bounds__(64, 4): cap VGPR at 128 (4 waves/SIMD). Round-12's 136 VGPR
// crossed the 128 occupancy cliff (m69) and halved resident waves.
__global__ __launch_bounds__(64, 4) void sb_main_mfma(
        const ushort* __restrict__ xt, const float* __restrict__ verts,
        const char* __restrict__ wsb, float* __restrict__ out) {
    __shared__ __align__(16) ushort stage[PT * 104];  // A tile [point][K..95], pad stride 104
    __shared__ __align__(16) ushort hst[PT * 72];     // gelu(h) A tile
    __shared__ float cst[PT * 4];                     // vertex coords
    __shared__ float dls[PT * 32];                    // delta outputs

    const int lane = threadIdx.x;
    const int l15 = lane & 15, lg = lane >> 4;
    const int half8 = (lane >> 5) * 8;                // sampling: point offset for this half-wave
    const int cp = lane & 31;                         // sampling: channel pair
    const int g0 = blockIdx.x * PT;
    const int b  = g0 / Nc;
    const unsigned* __restrict__ xtb32 = (const unsigned*)(xt + ((size_t)b << 24));

    const float*  bph = (const float*)(wsb + BIAS_PH);
    const float*  bn1 = (const float*)(wsb + BIAS_N1);
    const float*  bdl = (const float*)(wsb + BIAS_DL);
    const ushort* Wph = (const ushort*)(wsb + B_PH);
    const ushort* Wn1 = (const ushort*)(wsb + B_N1);
    const ushort* Wdh = (const ushort*)(wsb + B_DH);
    const ushort* Wdl = (const ushort*)(wsb + B_DLO);
    const ushort* Wn2 = (const ushort*)(wsb + B_N2);

    // zero-init A tile (pad cols 72..103 are MFMA-read vs zero weights; NaN*0=NaN otherwise)
#pragma unroll
    for (int i = 0; i < (PT * 104) / 64; ++i) stage[i * 64 + lane] = 0;

    float bias_p[4], bias_h[4], bias_d[2];
#pragma unroll
    for (int n = 0; n < 4; ++n) { bias_p[n] = bph[n*16 + l15]; bias_h[n] = bn1[n*16 + l15]; }
#pragma unroll
    for (int n = 0; n < 2; ++n) bias_d[n] = bdl[n*16 + l15];

    // init: verts -> cst + stage coord block (cols 64..71; 67.. zero, weights zero-padded)
    if (lane < PT) {
        const float* vp = verts + (size_t)(g0 + lane) * 3;
        float x = vp[0], y = vp[1], z = vp[2];
        cst[lane*4+0] = x; cst[lane*4+1] = y; cst[lane*4+2] = z;
        uint4 cw;
        cw.x = (unsigned)f2bf(x) | ((unsigned)f2bf(y) << 16);
        cw.y = (unsigned)f2bf(z);
        cw.z = 0u; cw.w = 0u;
        *(uint4*)(stage + lane * 104 + 64) = cw;
    }
    __syncthreads();

    // ---- sample column 0: half-wave point split, 64 dword gathers ----
#pragma unroll 4
    for (int pp = 0; pp < 8; ++pp) {
        int p = half8 + pp;
        sample_pair(xtb32, stage, cp, p, cst[p*4+0], cst[p*4+1], cst[p*4+2]);
    }
    __syncthreads();

    // ---- merged GEMM pass: ph + nh1(col0) + delta(hi+lo), K=96 ----
    f32x4 pf[4], nf[4], hh[4], dd[2];
#pragma unroll
    for (int n = 0; n < 4; ++n) {
        pf[n] = (f32x4){bias_p[n], bias_p[n], bias_p[n], bias_p[n]};
        hh[n] = (f32x4){bias_h[n], bias_h[n], bias_h[n], bias_h[n]};
        nf[n] = (f32x4){0.f, 0.f, 0.f, 0.f};
    }
#pragma unroll
    for (int n = 0; n < 2; ++n) dd[n] = (f32x4){bias_d[n], bias_d[n], bias_d[n], bias_d[n]};

#pragma unroll
    for (int kt = 0; kt < 3; ++kt) {
        bf16x8 a = *(const bf16x8*)(stage + l15 * 104 + kt * 32 + lg * 8);
#pragma unroll
        for (int n = 0; n < 4; ++n) {
            bf16x8 bw = *(const bf16x8*)(Wph + ((kt*4 + n) << 9) + lane * 8);
            pf[n] = __builtin_amdgcn_mfma_f32_16x16x32_bf16(a, bw, pf[n], 0, 0, 0);
            bf16x8 b1 = *(const bf16x8*)(Wn1 + ((kt*4 + n) << 9) + lane * 8);
            hh[n] = __builtin_amdgcn_mfma_f32_16x16x32_bf16(a, b1, hh[n], 0, 0, 0);
        }
#pragma unroll
        for (int n = 0; n < 2; ++n) {
            bf16x8 bh = *(const bf16x8*)(Wdh + ((kt*2 + n) << 9) + lane * 8);
            dd[n] = __builtin_amdgcn_mfma_f32_16x16x32_bf16(a, bh, dd[n], 0, 0, 0);
            bf16x8 bl = *(const bf16x8*)(Wdl + ((kt*2 + n) << 9) + lane * 8);
            dd[n] = __builtin_amdgcn_mfma_f32_16x16x32_bf16(a, bl, dd[n], 0, 0, 0);
        }
    }

    // D layout: row=(lg*4+r) [point], col=n*16+l15
#pragma unroll
    for (int n = 0; n < 2; ++n)
#pragma unroll
        for (int r = 0; r < 4; ++r)
            dls[(lg*4 + r) * 32 + n*16 + l15] = dd[n][r];
#pragma unroll
    for (int n = 0; n < 4; ++n)
#pragma unroll
        for (int r = 0; r < 4; ++r)
            hst[(lg*4 + r) * 72 + n*16 + l15] = f2bf(gelu_exact(hh[n][r]));
    __syncthreads();

    // ---- nh2 column 0 (K=64, 2 ksteps) ----
#pragma unroll
    for (int kt = 0; kt < 2; ++kt) {
        bf16x8 a = *(const bf16x8*)(hst + l15 * 72 + kt * 32 + lg * 8);
#pragma unroll
        for (int n = 0; n < 4; ++n) {
            bf16x8 bw = *(const bf16x8*)(Wn2 + ((kt*4 + n) << 9) + lane * 8);
            nf[n] = __builtin_amdgcn_mfma_f32_16x16x32_bf16(a, bw, nf[n], 0, 0, 0);
        }
    }

    // ---- neighbour columns 1..8 ----
    for (int k = 0; k < Kc; ++k) {
        // coord block cols 64..71 for this column
        if (lane < PT) {
            float x = cst[lane*4+0] + dls[lane*32 + 3*k + 0];
            float y = cst[lane*4+1] + dls[lane*32 + 3*k + 1];
            float z = cst[lane*4+2] + dls[lane*32 + 3*k + 2];
            uint4 cw;
            cw.x = (unsigned)f2bf(x) | ((unsigned)f2bf(y) << 16);
            cw.y = (unsigned)f2bf(z);
            cw.z = 0u; cw.w = 0u;
            *(uint4*)(stage + lane * 104 + 64) = cw;
        }
        // sample: half-wave point split, coords recomputed per lane (LDS broadcast)
#pragma unroll 4
        for (int pp = 0; pp < 8; ++pp) {
            int p = half8 + pp;
            float nx = cst[p*4+0] + dls[p*32 + 3*k + 0];
            float ny = cst[p*4+1] + dls[p*32 + 3*k + 1];
            float nz = cst[p*4+2] + dls[p*32 + 3*k + 2];
            sample_pair(xtb32, stage, cp, p, nx, ny, nz);
        }
        __syncthreads();

        f32x4 hk[4];
#pragma unroll
        for (int n = 0; n < 4; ++n) hk[n] = (f32x4){bias_h[n], bias_h[n], bias_h[n], bias_h[n]};
#pragma unroll
        for (int kt = 0; kt < 3; ++kt) {
            bf16x8 a = *(const bf16x8*)(stage + l15 * 104 + kt * 32 + lg * 8);
#pragma unroll
            for (int n = 0; n < 4; ++n) {
                bf16x8 b1 = *(const bf16x8*)(Wn1 + ((kt*4 + n) << 9) + lane * 8);
                hk[n] = __builtin_amdgcn_mfma_f32_16x16x32_bf16(a, b1, hk[n], 0, 0, 0);
            }
        }
#pragma unroll
        for (int n = 0; n < 4; ++n)
#pragma unroll
            for (int r = 0; r < 4; ++r)
                hst[(lg*4 + r) * 72 + n*16 + l15] = f2bf(gelu_exact(hk[n][r]));
        __syncthreads();

        const ushort* Wk = Wn2 + ((size_t)(k + 1) << 12);
#pragma unroll
        for (int kt = 0; kt < 2; ++kt) {
            bf16x8 a = *(const bf16x8*)(hst + l15 * 72 + kt * 32 + lg * 8);
#pragma unroll
            for (int n = 0; n < 4; ++n) {
                bf16x8 bw = *(const bf16x8*)(Wk + ((kt*4 + n) << 9) + lane * 8);
                nf[n] = __builtin_amdgcn_mfma_f32_16x16x32_bf16(a, bw, nf[n], 0, 0, 0);
            }
        }
    }

    // ---- store out[point][channel] = pf + nf (contiguous rows) ----
#pragma unroll
    for (int n = 0; n < 4; ++n)
#pragma unroll
        for (int r = 0; r < 4; ++r)
            out[(size_t)(g0 + lg*4 + r) * 64 + n*16 + l15] = pf[n][r] + nf[n][r];
}

// ---------------- correctness fallback (only if ws too small; slow, f32) ----------------
__global__ __launch_bounds__(64) void sb_fallback(
        const float* __restrict__ x, const float* __restrict__ verts,
        const float* __restrict__ shape_w, const float* __restrict__ shape_b,
        const float* __restrict__ delta_w, const float* __restrict__ delta_b,
        const float* __restrict__ ph_w, const float* __restrict__ ph_b,
        const float* __restrict__ nh1_w, const float* __restrict__ nh1_b,
        const float* __restrict__ nh2_w, float* __restrict__ out) {
    __shared__ float cp[72];
    __shared__ float hcol[64];
    __shared__ float dl[24];
    int lane = threadIdx.x;
    int g = blockIdx.x;
    int b = g / Nc;
    const float* xb = x + ((size_t)(b * 64 + lane) << 18);
    float vx = verts[g*3], vy = verts[g*3+1], vz = verts[g*3+2];
    cp[lane] = sample_cm(xb, vx, vy, vz);
    if (lane < 8) {
        float v = 0.0f;
        if      (lane == 0) v = vx;
        else if (lane == 1) v = vy;
        else if (lane == 2) v = vz;
        else if (lane < 7) {
            int i = lane - 3;
            v = 64.0f*(shape_w[i*4]+shape_w[i*4+1]+shape_w[i*4+2]+shape_w[i*4+3]) + shape_b[i];
        }
        cp[64 + lane] = v;
    }
    __syncthreads();
    float pfv = ph_b[lane];
    for (int j = 0; j < 67; ++j) pfv += ph_w[lane*67 + j] * cp[j];
    if (lane < 24) {
        float s = delta_b[lane];
        for (int j = 0; j < 71; ++j) s += delta_w[lane*71 + j] * cp[j];
        dl[lane] = s;
    }
    float h = nh1_b[lane];
    for (int j = 0; j < 67; ++j) h += nh1_w[lane*67 + j] * cp[j];
    hcol[lane] = gelu_exact(h);
    __syncthreads();
    float nfv = 0.0f;
    for (int c2 = 0; c2 < 64; ++c2) nfv += nh2_w[(lane*64 + c2)*9] * hcol[c2];
    for (int k = 0; k < 8; ++k) {
        __syncthreads();
        float nx = vx + dl[3*k], ny = vy + dl[3*k+1], nz = vz + dl[3*k+2];
        cp[lane] = sample_cm(xb, nx, ny, nz);
        if (lane < 3) cp[64 + lane] = (lane == 0) ? nx : (lane == 1) ? ny : nz;
        __syncthreads();
        float hv = nh1_b[lane];
        for (int j = 0; j < 67; ++j) hv += nh1_w[lane*67 + j] * cp[j];
        hcol[lane] = gelu_exact(hv);
        __syncthreads();
        for (int c2 = 0; c2 < 64; ++c2) nfv += nh2_w[(lane*64 + c2)*9 + k + 1] * hcol[c2];
    }
    out[(size_t)g * 64 + lane] = pfv + nfv;
}

// ---------------- launch ----------------
extern "C" void kernel_launch(void* const* d_in, const int* in_sizes, int n_in,
                              void* d_out, int out_size, void* d_ws, size_t ws_size,
                              hipStream_t stream) {
    const float* x       = (const float*)d_in[0];
    const float* verts   = (const float*)d_in[1];
    const float* shape_w = (const float*)d_in[2];
    const float* shape_b = (const float*)d_in[3];
    const float* delta_w = (const float*)d_in[4];
    const float* delta_b = (const float*)d_in[5];
    const float* ph_w    = (const float*)d_in[6];
    const float* ph_b    = (const float*)d_in[7];
    const float* nh1_w   = (const float*)d_in[8];
    const float* nh1_b   = (const float*)d_in[9];
    const float* nh2_w   = (const float*)d_in[10];
    float* out = (float*)d_out;
    char*  wsb = (char*)d_ws;

    const size_t need = XT_BYTE + XT_USHORTS * 2;
    if (ws_size >= need) {
        ushort* xt = (ushort*)(wsb + XT_BYTE);
        sb_pack<<<96, 256, 0, stream>>>(shape_w, shape_b, delta_w, delta_b,
                                        ph_w, ph_b, nh1_w, nh1_b, nh2_w, wsb);
        sb_transpose<<<Bc * 4096, 256, 0, stream>>>(x, xt);
        sb_main_mfma<<<NBLK, 64, 0, stream>>>(xt, verts, wsb, out);
    } else {
        sb_fallback<<<Bc * Nc, 64, 0, stream>>>(x, verts, shape_w, shape_b, delta_w, delta_b,
                                                ph_w, ph_b, nh1_w, nh1_b, nh2_w, out);
    }
}

// Round 14
// 228.498 us; speedup vs baseline: 2.7454x; 1.2521x over previous
//
#include <hip/hip_runtime.h>
#include <math.h>

// ---------------- problem constants ----------------
constexpr int Bc = 2, Cc = 64, Nc = 50000, Kc = 8;
constexpr int PT = 16;                       // points per wave (MFMA M dim)
constexpr int NBLK = (Bc * Nc) / PT;         // 6250, exact

// ---------------- ws byte layout (same as round 8) ----------------
constexpr int BIAS_PH = 16;                  // f32[64]
constexpr int BIAS_N1 = 272;                 // f32[64]
constexpr int BIAS_DL = 528;                 // f32[32] (sv folded, padded)
constexpr int B_PH  = 1024;                  // 12 frags * 1KB
constexpr int B_N1  = 13312;                 // 12 frags
constexpr int B_DH  = 25600;                 // 6 frags (delta hi)
constexpr int B_DLO = 31744;                 // 6 frags (delta lo)
constexpr int B_N2  = 37888;                 // 72 frags -> ends 111616
constexpr size_t XT_BYTE = 262144;           // bf16 volume starts here
constexpr size_t XT_USHORTS = (size_t)Bc * 64 * 64 * 64 * 64;

using bf16x8 = __attribute__((ext_vector_type(8))) short;
using f32x4  = __attribute__((ext_vector_type(4))) float;

// ---------------- helpers ----------------
__device__ __forceinline__ float gelu_exact(float v) {
    return 0.5f * v * (1.0f + erff(v * 0.70710678118654752f));
}
__device__ __forceinline__ ushort f2bf(float f) {           // RNE f32 -> bf16 bits
    unsigned u = __float_as_uint(f);
    unsigned r = (u + 0x7FFFu + ((u >> 16) & 1u)) >> 16;
    return (ushort)r;
}
__device__ __forceinline__ float bf2f(ushort u) {
    return __uint_as_float(((unsigned)u) << 16);
}
__device__ __forceinline__ float tri8(float v000, float v001, float v010, float v011,
                                      float v100, float v101, float v110, float v111,
                                      float fx, float fy, float fz) {
    float c00 = fmaf(fx, v001 - v000, v000);
    float c01 = fmaf(fx, v011 - v010, v010);
    float c10 = fmaf(fx, v101 - v100, v100);
    float c11 = fmaf(fx, v111 - v110, v110);
    float c0  = fmaf(fy, c01 - c00, c00);
    float c1  = fmaf(fy, c11 - c10, c10);
    return fmaf(fz, c1 - c0, c0);
}

// half-wave dword-pair sampling: lane handles channels (2cp, 2cp+1) of point p.
// 8 dword gathers (each: half-wave covers one full 64-ch corner line = 128B).
__device__ __forceinline__ void sample_pair(const unsigned* __restrict__ xtb32,
                                            ushort* __restrict__ stage,
                                            int cp, int p,
                                            float nx, float ny, float nz) {
    float ix = fminf(fmaxf((nx + 1.0f) * 31.5f, 0.0f), 63.0f);
    float iy = fminf(fmaxf((ny + 1.0f) * 31.5f, 0.0f), 63.0f);
    float iz = fminf(fmaxf((nz + 1.0f) * 31.5f, 0.0f), 63.0f);
    float fx0 = floorf(ix), fy0 = floorf(iy), fz0 = floorf(iz);
    int x0 = (int)fx0, y0 = (int)fy0, z0 = (int)fz0;
    float fx = ix - fx0, fy = iy - fy0, fz = iz - fz0;
    int dx = (x0 < 63) ? 32 : 0;          // +1 in x = +32 dwords (64 ushorts)
    int dy = (y0 < 63) ? 2048 : 0;        // +1 in y
    int dz = (z0 < 63) ? 131072 : 0;      // +1 in z
    const unsigned* r = xtb32 + ((((z0 << 12) + (y0 << 6) + x0) << 5) + cp);
    unsigned u000 = r[0],       u001 = r[dx];
    unsigned u010 = r[dy],      u011 = r[dy + dx];
    unsigned u100 = r[dz],      u101 = r[dz + dx];
    unsigned u110 = r[dz + dy], u111 = r[dz + dy + dx];
    float sa = tri8(bf2f((ushort)u000), bf2f((ushort)u001),
                    bf2f((ushort)u010), bf2f((ushort)u011),
                    bf2f((ushort)u100), bf2f((ushort)u101),
                    bf2f((ushort)u110), bf2f((ushort)u111), fx, fy, fz);
    float sb = tri8(bf2f((ushort)(u000 >> 16)), bf2f((ushort)(u001 >> 16)),
                    bf2f((ushort)(u010 >> 16)), bf2f((ushort)(u011 >> 16)),
                    bf2f((ushort)(u100 >> 16)), bf2f((ushort)(u101 >> 16)),
                    bf2f((ushort)(u110 >> 16)), bf2f((ushort)(u111 >> 16)), fx, fy, fz);
    *(unsigned*)(stage + p * 104 + 2 * cp) =
        (unsigned)f2bf(sa) | ((unsigned)f2bf(sb) << 16);
}

// ---- fallback (channel-major f32) sampling ----
__device__ __forceinline__ float sample_cm(const float* __restrict__ xb,
                                           float gx, float gy, float gz) {
    float ix = fminf(fmaxf((gx + 1.0f) * 31.5f, 0.0f), 63.0f);
    float iy = fminf(fmaxf((gy + 1.0f) * 31.5f, 0.0f), 63.0f);
    float iz = fminf(fmaxf((gz + 1.0f) * 31.5f, 0.0f), 63.0f);
    float fx0 = floorf(ix), fy0 = floorf(iy), fz0 = floorf(iz);
    int x0 = (int)fx0, y0 = (int)fy0, z0 = (int)fz0;
    float fx = ix - fx0, fy = iy - fy0, fz = iz - fz0;
    int x1 = (x0 < 63) ? x0 + 1 : 63;
    int dy = (y0 < 63) ? 64 : 0;
    int dz = (z0 < 63) ? 4096 : 0;
    const float* r = xb + ((z0 << 12) + (y0 << 6));
    float v000 = r[x0],           v001 = r[x1];
    float v010 = r[x0 + dy],      v011 = r[x1 + dy];
    float v100 = r[x0 + dz],      v101 = r[x1 + dz];
    float v110 = r[x0 + dy + dz], v111 = r[x1 + dy + dz];
    return tri8(v000, v001, v010, v011, v100, v101, v110, v111, fx, fy, fz);
}

// ---------------- weight packing: B-fragment lane order, bf16 (unchanged) ----------------
__global__ void sb_pack(const float* __restrict__ shape_w, const float* __restrict__ shape_b,
                        const float* __restrict__ delta_w, const float* __restrict__ delta_b,
                        const float* __restrict__ ph_w, const float* __restrict__ ph_b,
                        const float* __restrict__ nh1_w, const float* __restrict__ nh1_b,
                        const float* __restrict__ nh2_w, char* __restrict__ wsb) {
    int tid = blockIdx.x * blockDim.x + threadIdx.x;
    int nt  = gridDim.x * blockDim.x;
    float*  bph = (float*)(wsb + BIAS_PH);
    float*  bn1 = (float*)(wsb + BIAS_N1);
    float*  bdl = (float*)(wsb + BIAS_DL);
    ushort* wph = (ushort*)(wsb + B_PH);
    ushort* wn1 = (ushort*)(wsb + B_N1);
    ushort* wdh = (ushort*)(wsb + B_DH);
    ushort* wdl = (ushort*)(wsb + B_DLO);
    ushort* wn2 = (ushort*)(wsb + B_N2);

    for (int e = tid; e < 64; e += nt) { bph[e] = ph_b[e]; bn1[e] = nh1_b[e]; }
    for (int e = tid; e < 32; e += nt) {
        float v = 0.0f;
        if (e < 24) {
            v = delta_b[e];
#pragma unroll
            for (int i = 0; i < 4; ++i) {   // fold shape_vec (constant) into bias, f32 exact
                float sv = 64.0f * (shape_w[i*4] + shape_w[i*4+1] + shape_w[i*4+2] + shape_w[i*4+3])
                         + shape_b[i];
                v += sv * delta_w[e * 71 + 67 + i];
            }
        }
        bdl[e] = v;
    }
    for (int e = tid; e < 6144; e += nt) {
        int frag = e >> 9, lane = (e >> 3) & 63, j = e & 7;
        int kt = frag >> 2, n = frag & 3;
        int k = kt * 32 + ((lane >> 4) << 3) + j;
        int col = n * 16 + (lane & 15);
        wph[e] = (k < 67) ? f2bf(ph_w[col * 67 + k])  : (ushort)0;
        wn1[e] = (k < 67) ? f2bf(nh1_w[col * 67 + k]) : (ushort)0;
    }
    for (int e = tid; e < 3072; e += nt) {
        int frag = e >> 9, lane = (e >> 3) & 63, j = e & 7;
        int kt = frag >> 1, n = frag & 1;
        int k = kt * 32 + ((lane >> 4) << 3) + j;
        int col = n * 16 + (lane & 15);
        float w = (col < 24 && k < 67) ? delta_w[col * 71 + k] : 0.0f;
        ushort hi = f2bf(w);
        wdh[e] = hi;
        wdl[e] = f2bf(w - bf2f(hi));
    }
    for (int e = tid; e < 36864; e += nt) {
        int frag = e >> 9, lane = (e >> 3) & 63, j = e & 7;
        int c9 = frag >> 3, kt = (frag >> 2) & 1, n = frag & 3;
        int k = kt * 32 + ((lane >> 4) << 3) + j;
        int c = n * 16 + (lane & 15);
        wn2[e] = f2bf(nh2_w[(c * 64 + k) * 9 + c9]);
    }
}

// ---------------- transpose x [B,C,64^3] f32 -> xt [B,64^3,C] bf16 (unchanged) ----------------
__global__ __launch_bounds__(256) void sb_transpose(const float* __restrict__ x,
                                                    ushort* __restrict__ xt) {
    __shared__ float tile[64][65];
    int blk = blockIdx.x;
    int b = blk >> 12, zy = blk & 4095;
    const float* __restrict__ src = x + ((size_t)b << 24) + zy * 64;
    unsigned* __restrict__ dst32 = (unsigned*)(xt + ((size_t)b << 24) + (size_t)zy * 4096);
    int t = threadIdx.x;
    int xx = t & 63, c0 = t >> 6;
#pragma unroll
    for (int i = 0; i < 16; ++i) {
        int c = i * 4 + c0;
        tile[c][xx] = src[((size_t)c << 18) + xx];
    }
    __syncthreads();
    int cp = t & 31, xs0 = t >> 5;
#pragma unroll
    for (int i = 0; i < 8; ++i) {
        int xs = i * 8 + xs0;
        unsigned lo = f2bf(tile[cp * 2][xs]);
        unsigned hi = f2bf(tile[cp * 2 + 1][xs]);
        dst32[xs * 32 + cp] = lo | (hi << 16);
    }
}

// ---------------- main MFMA kernel: 1 wave = 16 points, register-slim ----------------
// Register-demand restructure: split GEMM sweeps (peak acc 24 not 56), pf parked
// in LDS across the k-loop, biases reloaded per use. Target <=85 VGPR (6 w/SIMD).
__global__ __launch_bounds__(64, 6) void sb_main_mfma(
        const ushort* __restrict__ xt, const float* __restrict__ verts,
        const char* __restrict__ wsb, float* __restrict__ out) {
    __shared__ __align__(16) ushort stage[PT * 104];  // A tile [point][K..95], pad stride 104
    __shared__ __align__(16) ushort hst[PT * 72];     // gelu(h) A tile
    __shared__ float pfs[PT * 64];                    // parked point-head results (4 KB)
    __shared__ float cst[PT * 4];                     // vertex coords
    __shared__ float dls[PT * 32];                    // delta outputs

    const int lane = threadIdx.x;
    const int l15 = lane & 15, lg = lane >> 4;
    const int half8 = (lane >> 5) * 8;                // sampling: point offset for this half-wave
    const int cp = lane & 31;                         // sampling: channel pair
    const int g0 = blockIdx.x * PT;
    const int b  = g0 / Nc;
    const unsigned* __restrict__ xtb32 = (const unsigned*)(xt + ((size_t)b << 24));

    const float*  bph = (const float*)(wsb + BIAS_PH);
    const float*  bn1 = (const float*)(wsb + BIAS_N1);
    const float*  bdl = (const float*)(wsb + BIAS_DL);
    const ushort* Wph = (const ushort*)(wsb + B_PH);
    const ushort* Wn1 = (const ushort*)(wsb + B_N1);
    const ushort* Wdh = (const ushort*)(wsb + B_DH);
    const ushort* Wdl = (const ushort*)(wsb + B_DLO);
    const ushort* Wn2 = (const ushort*)(wsb + B_N2);

    // zero-init A tile (pad cols 72..103 are MFMA-read vs zero weights; NaN*0=NaN otherwise)
#pragma unroll
    for (int i = 0; i < (PT * 104) / 64; ++i) stage[i * 64 + lane] = 0;

    // init: verts -> cst + stage coord block (cols 64..71; 67.. zero, weights zero-padded)
    if (lane < PT) {
        const float* vp = verts + (size_t)(g0 + lane) * 3;
        float x = vp[0], y = vp[1], z = vp[2];
        cst[lane*4+0] = x; cst[lane*4+1] = y; cst[lane*4+2] = z;
        uint4 cw;
        cw.x = (unsigned)f2bf(x) | ((unsigned)f2bf(y) << 16);
        cw.y = (unsigned)f2bf(z);
        cw.z = 0u; cw.w = 0u;
        *(uint4*)(stage + lane * 104 + 64) = cw;
    }
    __syncthreads();

    // ---- sample column 0: half-wave point split, 64 dword gathers ----
#pragma unroll 4
    for (int pp = 0; pp < 8; ++pp) {
        int p = half8 + pp;
        sample_pair(xtb32, stage, cp, p, cst[p*4+0], cst[p*4+1], cst[p*4+2]);
    }
    __syncthreads();

    // ---- sweep 1: point head + delta (hi+lo), K=96; peak acc = 24 regs ----
    {
        f32x4 pf[4], dd[2];
#pragma unroll
        for (int n = 0; n < 4; ++n) {
            float bp = bph[n*16 + l15];
            pf[n] = (f32x4){bp, bp, bp, bp};
        }
#pragma unroll
        for (int n = 0; n < 2; ++n) {
            float bd = bdl[n*16 + l15];
            dd[n] = (f32x4){bd, bd, bd, bd};
        }
#pragma unroll
        for (int kt = 0; kt < 3; ++kt) {
            bf16x8 a = *(const bf16x8*)(stage + l15 * 104 + kt * 32 + lg * 8);
#pragma unroll
            for (int n = 0; n < 4; ++n) {
                bf16x8 bw = *(const bf16x8*)(Wph + ((kt*4 + n) << 9) + lane * 8);
                pf[n] = __builtin_amdgcn_mfma_f32_16x16x32_bf16(a, bw, pf[n], 0, 0, 0);
            }
#pragma unroll
            for (int n = 0; n < 2; ++n) {
                bf16x8 bh = *(const bf16x8*)(Wdh + ((kt*2 + n) << 9) + lane * 8);
                dd[n] = __builtin_amdgcn_mfma_f32_16x16x32_bf16(a, bh, dd[n], 0, 0, 0);
                bf16x8 bl = *(const bf16x8*)(Wdl + ((kt*2 + n) << 9) + lane * 8);
                dd[n] = __builtin_amdgcn_mfma_f32_16x16x32_bf16(a, bl, dd[n], 0, 0, 0);
            }
        }
        // D layout: row=(lg*4+r) [point], col=n*16+l15 ; park pf in LDS, dd in dls
#pragma unroll
        for (int n = 0; n < 2; ++n)
#pragma unroll
            for (int r = 0; r < 4; ++r)
                dls[(lg*4 + r) * 32 + n*16 + l15] = dd[n][r];
#pragma unroll
        for (int n = 0; n < 4; ++n)
#pragma unroll
            for (int r = 0; r < 4; ++r)
                pfs[(lg*4 + r) * 64 + n*16 + l15] = pf[n][r];
    }

    // ---- sweep 2: nh1 column 0, K=96; acc = 16 regs ----
    {
        f32x4 hh[4];
#pragma unroll
        for (int n = 0; n < 4; ++n) {
            float bh = bn1[n*16 + l15];
            hh[n] = (f32x4){bh, bh, bh, bh};
        }
#pragma unroll
        for (int kt = 0; kt < 3; ++kt) {
            bf16x8 a = *(const bf16x8*)(stage + l15 * 104 + kt * 32 + lg * 8);
#pragma unroll
            for (int n = 0; n < 4; ++n) {
                bf16x8 b1 = *(const bf16x8*)(Wn1 + ((kt*4 + n) << 9) + lane * 8);
                hh[n] = __builtin_amdgcn_mfma_f32_16x16x32_bf16(a, b1, hh[n], 0, 0, 0);
            }
        }
#pragma unroll
        for (int n = 0; n < 4; ++n)
#pragma unroll
            for (int r = 0; r < 4; ++r)
                hst[(lg*4 + r) * 72 + n*16 + l15] = f2bf(gelu_exact(hh[n][r]));
    }
    __syncthreads();

    // ---- nh2 column 0 (K=64, 2 ksteps); nf persists (16 regs) ----
    f32x4 nf[4];
#pragma unroll
    for (int n = 0; n < 4; ++n) nf[n] = (f32x4){0.f, 0.f, 0.f, 0.f};
#pragma unroll
    for (int kt = 0; kt < 2; ++kt) {
        bf16x8 a = *(const bf16x8*)(hst + l15 * 72 + kt * 32 + lg * 8);
#pragma unroll
        for (int n = 0; n < 4; ++n) {
            bf16x8 bw = *(const bf16x8*)(Wn2 + ((kt*4 + n) << 9) + lane * 8);
            nf[n] = __builtin_amdgcn_mfma_f32_16x16x32_bf16(a, bw, nf[n], 0, 0, 0);
        }
    }

    // ---- neighbour columns 1..8 ----
    for (int k = 0; k < Kc; ++k) {
        // coord block cols 64..71 for this column
        if (lane < PT) {
            float x = cst[lane*4+0] + dls[lane*32 + 3*k + 0];
            float y = cst[lane*4+1] + dls[lane*32 + 3*k + 1];
            float z = cst[lane*4+2] + dls[lane*32 + 3*k + 2];
            uint4 cw;
            cw.x = (unsigned)f2bf(x) | ((unsigned)f2bf(y) << 16);
            cw.y = (unsigned)f2bf(z);
            cw.z = 0u; cw.w = 0u;
            *(uint4*)(stage + lane * 104 + 64) = cw;
        }
        // sample: half-wave point split, coords recomputed per lane (LDS broadcast)
#pragma unroll 4
        for (int pp = 0; pp < 8; ++pp) {
            int p = half8 + pp;
            float nx = cst[p*4+0] + dls[p*32 + 3*k + 0];
            float ny = cst[p*4+1] + dls[p*32 + 3*k + 1];
            float nz = cst[p*4+2] + dls[p*32 + 3*k + 2];
            sample_pair(xtb32, stage, cp, p, nx, ny, nz);
        }
        __syncthreads();

        f32x4 hk[4];
#pragma unroll
        for (int n = 0; n < 4; ++n) {
            float bh = bn1[n*16 + l15];         // reload per column (L1-resident)
            hk[n] = (f32x4){bh, bh, bh, bh};
        }
#pragma unroll
        for (int kt = 0; kt < 3; ++kt) {
            bf16x8 a = *(const bf16x8*)(stage + l15 * 104 + kt * 32 + lg * 8);
#pragma unroll
            for (int n = 0; n < 4; ++n) {
                bf16x8 b1 = *(const bf16x8*)(Wn1 + ((kt*4 + n) << 9) + lane * 8);
                hk[n] = __builtin_amdgcn_mfma_f32_16x16x32_bf16(a, b1, hk[n], 0, 0, 0);
            }
        }
#pragma unroll
        for (int n = 0; n < 4; ++n)
#pragma unroll
            for (int r = 0; r < 4; ++r)
                hst[(lg*4 + r) * 72 + n*16 + l15] = f2bf(gelu_exact(hk[n][r]));
        __syncthreads();

        const ushort* Wk = Wn2 + ((size_t)(k + 1) << 12);
#pragma unroll
        for (int kt = 0; kt < 2; ++kt) {
            bf16x8 a = *(const bf16x8*)(hst + l15 * 72 + kt * 32 + lg * 8);
#pragma unroll
            for (int n = 0; n < 4; ++n) {
                bf16x8 bw = *(const bf16x8*)(Wk + ((kt*4 + n) << 9) + lane * 8);
                nf[n] = __builtin_amdgcn_mfma_f32_16x16x32_bf16(a, bw, nf[n], 0, 0, 0);
            }
        }
    }

    // ---- store out[point][channel] = pfs + nf (contiguous rows) ----
#pragma unroll
    for (int n = 0; n < 4; ++n)
#pragma unroll
        for (int r = 0; r < 4; ++r)
            out[(size_t)(g0 + lg*4 + r) * 64 + n*16 + l15] =
                pfs[(lg*4 + r) * 64 + n*16 + l15] + nf[n][r];
}

// ---------------- correctness fallback (only if ws too small; slow, f32) ----------------
__global__ __launch_bounds__(64) void sb_fallback(
        const float* __restrict__ x, const float* __restrict__ verts,
        const float* __restrict__ shape_w, const float* __restrict__ shape_b,
        const float* __restrict__ delta_w, const float* __restrict__ delta_b,
        const float* __restrict__ ph_w, const float* __restrict__ ph_b,
        const float* __restrict__ nh1_w, const float* __restrict__ nh1_b,
        const float* __restrict__ nh2_w, float* __restrict__ out) {
    __shared__ float cp[72];
    __shared__ float hcol[64];
    __shared__ float dl[24];
    int lane = threadIdx.x;
    int g = blockIdx.x;
    int b = g / Nc;
    const float* xb = x + ((size_t)(b * 64 + lane) << 18);
    float vx = verts[g*3], vy = verts[g*3+1], vz = verts[g*3+2];
    cp[lane] = sample_cm(xb, vx, vy, vz);
    if (lane < 8) {
        float v = 0.0f;
        if      (lane == 0) v = vx;
        else if (lane == 1) v = vy;
        else if (lane == 2) v = vz;
        else if (lane < 7) {
            int i = lane - 3;
            v = 64.0f*(shape_w[i*4]+shape_w[i*4+1]+shape_w[i*4+2]+shape_w[i*4+3]) + shape_b[i];
        }
        cp[64 + lane] = v;
    }
    __syncthreads();
    float pfv = ph_b[lane];
    for (int j = 0; j < 67; ++j) pfv += ph_w[lane*67 + j] * cp[j];
    if (lane < 24) {
        float s = delta_b[lane];
        for (int j = 0; j < 71; ++j) s += delta_w[lane*71 + j] * cp[j];
        dl[lane] = s;
    }
    float h = nh1_b[lane];
    for (int j = 0; j < 67; ++j) h += nh1_w[lane*67 + j] * cp[j];
    hcol[lane] = gelu_exact(h);
    __syncthreads();
    float nfv = 0.0f;
    for (int c2 = 0; c2 < 64; ++c2) nfv += nh2_w[(lane*64 + c2)*9] * hcol[c2];
    for (int k = 0; k < 8; ++k) {
        __syncthreads();
        float nx = vx + dl[3*k], ny = vy + dl[3*k+1], nz = vz + dl[3*k+2];
        cp[lane] = sample_cm(xb, nx, ny, nz);
        if (lane < 3) cp[64 + lane] = (lane == 0) ? nx : (lane == 1) ? ny : nz;
        __syncthreads();
        float hv = nh1_b[lane];
        for (int j = 0; j < 67; ++j) hv += nh1_w[lane*67 + j] * cp[j];
        hcol[lane] = gelu_exact(hv);
        __syncthreads();
        for (int c2 = 0; c2 < 64; ++c2) nfv += nh2_w[(lane*64 + c2)*9 + k + 1] * hcol[c2];
    }
    out[(size_t)g * 64 + lane] = pfv + nfv;
}

// ---------------- launch ----------------
extern "C" void kernel_launch(void* const* d_in, const int* in_sizes, int n_in,
                              void* d_out, int out_size, void* d_ws, size_t ws_size,
                              hipStream_t stream) {
    const float* x       = (const float*)d_in[0];
    const float* verts   = (const float*)d_in[1];
    const float* shape_w = (const float*)d_in[2];
    const float* shape_b = (const float*)d_in[3];
    const float* delta_w = (const float*)d_in[4];
    const float* delta_b = (const float*)d_in[5];
    const float* ph_w    = (const float*)d_in[6];
    const float* ph_b    = (const float*)d_in[7];
    const float* nh1_w   = (const float*)d_in[8];
    const float* nh1_b   = (const float*)d_in[9];
    const float* nh2_w   = (const float*)d_in[10];
    float* out = (float*)d_out;
    char*  wsb = (char*)d_ws;

    const size_t need = XT_BYTE + XT_USHORTS * 2;
    if (ws_size >= need) {
        ushort* xt = (ushort*)(wsb + XT_BYTE);
        sb_pack<<<96, 256, 0, stream>>>(shape_w, shape_b, delta_w, delta_b,
                                        ph_w, ph_b, nh1_w, nh1_b, nh2_w, wsb);
        sb_transpose<<<Bc * 4096, 256, 0, stream>>>(x, xt);
        sb_main_mfma<<<NBLK, 64, 0, stream>>>(xt, verts, wsb, out);
    } else {
        sb_fallback<<<Bc * Nc, 64, 0, stream>>>(x, verts, shape_w, shape_b, delta_w, delta_b,
                                                ph_w, ph_b, nh1_w, nh1_b, nh2_w, out);
    }
}